// Round 1
// 165.665 us; speedup vs baseline: 1.0022x; 1.0022x over previous
//
#include <hip/hip_runtime.h>
#include <stdint.h>

#define S_LEN 2048
#define D_MODEL 1024
#define NH 16
#define DKV 64

typedef unsigned short u16;
typedef __bf16 bf16x8 __attribute__((ext_vector_type(8)));
typedef float f32x4 __attribute__((ext_vector_type(4)));

__device__ __forceinline__ u16 f2bf(float f) {
  union { float f; uint32_t u; } v; v.f = f;
  uint32_t r = v.u + 0x7FFFu + ((v.u >> 16) & 1u);
  return (u16)(r >> 16);
}
// pack two positive floats to bf16x2 (cheap round; softmax-normalized later)
__device__ __forceinline__ uint32_t pkbf(float lo, float hi) {
  union { float f; uint32_t u; } a, b; a.f = lo; b.f = hi;
  return ((b.u + 0x8000u) & 0xFFFF0000u) | ((a.u + 0x8000u) >> 16);
}
// async global->LDS 16B: lds dest is WAVE-UNIFORM base; HW adds lane*16
__device__ __forceinline__ void gl16(const u16* g, u16* l) {
  __builtin_amdgcn_global_load_lds(
      (const __attribute__((address_space(1))) unsigned int*)g,
      (__attribute__((address_space(3))) unsigned int*)l, 16, 0, 0);
}

// ---------- fused preprocessing: conv QKV + transpose Wq/Wk/Wv + transpose Wo ----------
// 1D grid: [0,6144) conv, [6144,9216) qkvw transpose, [9216,10240) Wo transpose
__global__ __launch_bounds__(256) void prep_k(
    const float* __restrict__ Q, const float* __restrict__ K,
    const float* __restrict__ V, const float* __restrict__ Wq,
    const float* __restrict__ Wk, const float* __restrict__ Wv,
    const float* __restrict__ Wo, u16* __restrict__ QKVb,
    u16* __restrict__ Wqt, u16* __restrict__ Wkt, u16* __restrict__ Wvt,
    u16* __restrict__ Wot) {
  __shared__ float tile[32][33];
  const int idx = blockIdx.x;
  if (idx < 6144) {
    const int z = idx >> 11, blk = idx & 2047;
    const float* src = (z == 0) ? Q : (z == 1) ? K : V;
    u16* dst = QKVb + (size_t)z * S_LEN * D_MODEL;
    size_t i = ((size_t)blk * 256 + threadIdx.x) * 4;
    const float4 v = *(const float4*)(src + i);
    union { u16 h[4]; uint2 u2; } o;
    o.h[0] = f2bf(v.x); o.h[1] = f2bf(v.y); o.h[2] = f2bf(v.z); o.h[3] = f2bf(v.w);
    *(uint2*)(dst + i) = o.u2;
    return;
  }
  const float* ip; u16* op; int R, C, r0, c0;
  if (idx < 9216) {
    int t = idx - 6144;
    int which = t >> 10, head = (t & 1023) >> 6, tl = t & 63;
    ip = ((which == 0) ? Wq : (which == 1) ? Wk : Wv) + (size_t)head * D_MODEL * DKV;
    op = ((which == 0) ? Wqt : (which == 1) ? Wkt : Wvt) + (size_t)head * D_MODEL * DKV;
    R = D_MODEL; C = DKV; c0 = (tl & 1) * 32; r0 = (tl >> 1) * 32;
  } else {
    int t = idx - 9216;
    ip = Wo; op = Wot; R = D_MODEL; C = D_MODEL;
    c0 = (t & 31) * 32; r0 = (t >> 5) * 32;
  }
  int tr = threadIdx.x >> 5, tc = threadIdx.x & 31;
#pragma unroll
  for (int i = 0; i < 4; i++)
    tile[tr + i * 8][tc] = ip[(size_t)(r0 + tr + i * 8) * C + c0 + tc];
  __syncthreads();
#pragma unroll
  for (int i = 0; i < 4; i++) {
    int c = tr + i * 8;
    op[(size_t)(c0 + c) * R + r0 + tc] = f2bf(tile[tc][c]);
  }
}

// ---------- projection GEMM m97-style: 128x128 tile, BK=64, async dbuf, 1 barrier/iter ----------
// 1D grid 384, XCD-swizzled: logical l = (bid%8)*48 + bid/8; l = z*128 + m*8 + n
// (n fastest). Per-XCD chunk: one z, 6 m-rows x all n -> A 1.5MB + B 2MB < 4MB L2.
__global__ __launch_bounds__(256, 2) void proj_gemm_k(
    const u16* __restrict__ qkvb, const u16* __restrict__ Wqt,
    const u16* __restrict__ Wkt, const u16* __restrict__ Wvt,
    const float* __restrict__ bq, const float* __restrict__ bk,
    const float* __restrict__ bv,
    u16* __restrict__ qb, u16* __restrict__ kb, u16* __restrict__ vT) {
  const int bid = blockIdx.x;
  const int l = (bid & 7) * 48 + (bid >> 3);   // bijective: 384 = 8*48
  const int z = l >> 7, rem = l & 127;
  const int m0 = (rem >> 3) * 128, n0 = (rem & 7) * 128;
  const u16* A = qkvb + (size_t)z * S_LEN * D_MODEL;
  const u16* Bt = (z == 0) ? Wqt : (z == 1) ? Wkt : Wvt;
  const float* bias = (z == 0) ? bq : (z == 1) ? bk : bv;
  const float scale = (z == 0) ? 0.18033688f : 1.0f;  // (1/8)*log2(e) folded into q

  __shared__ __align__(16) u16 smem[4 * 8192];  // A0 A1 B0 B1 (16KB each)
  const int tid = threadIdx.x;
  const int w = tid >> 6, lane = tid & 63, quad = lane >> 4, l15 = lane & 15;
  const int wm = (w >> 1) * 64, wn = (w & 1) * 64;
  const int pb = w * 256;

  f32x4 acc[4][4] = {};

  {
    u16* As = smem; u16* Bs = smem + 16384;
#pragma unroll
    for (int e = 0; e < 4; e++) {
      int p = pb + e * 64 + lane;
      int r = p >> 3, cg = (p & 7) ^ (r & 7);
      gl16(&A[(size_t)(m0 + r) * D_MODEL + cg * 8], As + (pb + e * 64) * 8);
      gl16(&Bt[(size_t)(n0 + r) * D_MODEL + cg * 8], Bs + (pb + e * 64) * 8);
    }
  }
  for (int it = 0; it < 16; it++) {
    __syncthreads();
    if (it < 15) {
      const int k0 = (it + 1) * 64;
      u16* As = smem + ((it + 1) & 1) * 8192;
      u16* Bs = smem + 16384 + ((it + 1) & 1) * 8192;
#pragma unroll
      for (int e = 0; e < 4; e++) {
        int p = pb + e * 64 + lane;
        int r = p >> 3, cg = (p & 7) ^ (r & 7);
        gl16(&A[(size_t)(m0 + r) * D_MODEL + k0 + cg * 8], As + (pb + e * 64) * 8);
        gl16(&Bt[(size_t)(n0 + r) * D_MODEL + k0 + cg * 8], Bs + (pb + e * 64) * 8);
      }
    }
    const u16* As = smem + (it & 1) * 8192;
    const u16* Bs = smem + 16384 + (it & 1) * 8192;
#pragma unroll
    for (int kc = 0; kc < 2; kc++) {
      bf16x8 af[4], bfr[4];
      const int c = kc * 4 + quad;
#pragma unroll
      for (int t = 0; t < 4; t++) {
        int ma = wm + t * 16 + l15, na = wn + t * 16 + l15;
        af[t] = *(const bf16x8*)&As[(ma * 8 + (c ^ (ma & 7))) * 8];
        bfr[t] = *(const bf16x8*)&Bs[(na * 8 + (c ^ (na & 7))) * 8];
      }
#pragma unroll
      for (int tm = 0; tm < 4; tm++)
#pragma unroll
        for (int tn = 0; tn < 4; tn++)
          acc[tm][tn] = __builtin_amdgcn_mfma_f32_16x16x32_bf16(af[tm], bfr[tn], acc[tm][tn], 0, 0, 0);
    }
  }

  if (z < 2) {
    u16* O = (z == 0) ? qb : kb;
#pragma unroll
    for (int tm = 0; tm < 4; tm++)
#pragma unroll
      for (int tn = 0; tn < 4; tn++)
#pragma unroll
        for (int r = 0; r < 4; r++) {
          int row = m0 + wm + tm * 16 + quad * 4 + r;
          int col = n0 + wn + tn * 16 + l15;
          O[(size_t)row * D_MODEL + col] = f2bf((acc[tm][tn][r] + bias[col]) * scale);
        }
  } else {
#pragma unroll
    for (int tm = 0; tm < 4; tm++)
#pragma unroll
      for (int tn = 0; tn < 4; tn++) {
        int col = n0 + wn + tn * 16 + l15;
        int row0 = m0 + wm + tm * 16 + quad * 4;
        float b = bias[col];
        union { u16 h[4]; uint2 u2; } o;
#pragma unroll
        for (int r = 0; r < 4; r++) o.h[r] = f2bf(acc[tm][tn][r] + b);
        *(uint2*)&vT[(size_t)col * S_LEN + row0] = o.u2;
      }
  }
}

// ---------- attention: gl16 async dbuf K/V, single barrier/iter, 16x16 high-ILP body ----------
// 512 thr = 8 waves = {4 q-subs(16q)} x {2 KV halves}; q-tile 64; t-tile 32/iter, 32 iters.
// 1D grid 512, XCD-swizzled: logical l = (bid%8)*64 + bid/8; l = h*32 + qblk
// -> each XCD owns 2 heads; K+V working set 2*(256+256)KB = 1MB, L2-resident.
__global__ __launch_bounds__(512) void attn_k(
    const u16* __restrict__ qb, const u16* __restrict__ kb,
    const u16* __restrict__ vT, u16* __restrict__ conc) {
  const int bid = blockIdx.x;
  const int l = (bid & 7) * 64 + (bid >> 3);   // bijective: 512 = 8*64
  const int h = l >> 5, qblk = (l & 31) * 64;
  const int tid = threadIdx.x;
  const int w = tid >> 6, lane = tid & 63, quad = lane >> 4, l15 = lane & 15;
  const int half = w >> 2, wq = w & 3;
  const int q0 = qblk + wq * 16;

  // u16: K[2 half][2 buf][256ch] @0 (16KB), V[2][2][256ch] @8192 (16KB), P[8][16*72] @16384 (18KB)
  // epilogue overlays @0 as float Osh[8][16][68] + lsh[8][16] (35.3KB < 50KB)
  __shared__ __align__(16) u16 smem[25600];
  u16* Kh = smem + half * 4096;
  u16* Vh = smem + 8192 + half * 4096;
  u16* Pw = smem + 16384 + w * 1152;

  // Q B-frags (n=q=l15, k=dk=kc*32+quad*8+j); q pre-scaled by (1/8)*log2(e)
  bf16x8 qf[2];
#pragma unroll
  for (int kc = 0; kc < 2; kc++)
    qf[kc] = *(const bf16x8*)&qb[(size_t)(q0 + l15) * D_MODEL + h * 64 + kc * 32 + quad * 8];

  const u16* kbase = kb + (size_t)h * 64;
  const u16* vbase = vT + (size_t)(h * 64) * S_LEN;

  // per-wave staging: 1 K chunk + 1 V chunk per lane per iter
  const int p = wq * 64 + lane;                   // 0..255
  const int kr = p >> 3, kcg = (p & 7) ^ (kr & 7);
  const int vr = p >> 2, vcg = (p & 3) ^ (vr & 3);
  const size_t kgoff = (size_t)kr * D_MODEL + kcg * 8;
  const size_t vgoff = (size_t)vr * S_LEN + vcg * 8;
  const int ldsoff = wq * 64 * 8;                 // wave-uniform dest (HW adds lane*16)

  f32x4 oacc[4] = {};
  float lsum = 0.f;

  {  // preload it=0 into buf0
    const int t0 = half * 1024;
    gl16(kbase + (size_t)t0 * D_MODEL + kgoff, Kh + ldsoff);
    gl16(vbase + t0 + vgoff, Vh + ldsoff);
  }

  for (int it = 0; it < 32; it++) {
    __syncthreads();  // buf[it&1] staged (compiler drains vmcnt before barrier)
    if (it < 31) {    // prefetch buf[(it+1)&1]; stays in flight across this compute
      const int t0n = half * 1024 + (it + 1) * 32;
      u16* Kd = Kh + ((it + 1) & 1) * 2048;
      u16* Vd = Vh + ((it + 1) & 1) * 2048;
      gl16(kbase + (size_t)t0n * D_MODEL + kgoff, Kd + ldsoff);
      gl16(vbase + t0n + vgoff, Vd + ldsoff);
    }
    const u16* Kc = Kh + (it & 1) * 2048;
    const u16* Vc = Vh + (it & 1) * 2048;

    // Sᵀ = K·Qᵀ : 2 independent chains (tn), depth 2 (kc)
    f32x4 sacc[2] = {};
#pragma unroll
    for (int kc = 0; kc < 2; kc++)
#pragma unroll
      for (int tn = 0; tn < 2; tn++) {
        int rr = tn * 16 + l15;
        bf16x8 ka = *(const bf16x8*)&Kc[(rr * 8 + ((kc * 4 + quad) ^ (rr & 7))) * 8];
        sacc[tn] = __builtin_amdgcn_mfma_f32_16x16x32_bf16(ka, qf[kc], sacc[tn], 0, 0, 0);
      }

    // p = 2^s (log2e folded into q); lane holds Sᵀ[t=tn*16+quad*4+r][q=l15]
#pragma unroll
    for (int tn = 0; tn < 2; tn++) {
      float p0 = exp2f(sacc[tn][0]);
      float p1 = exp2f(sacc[tn][1]);
      float p2 = exp2f(sacc[tn][2]);
      float p3 = exp2f(sacc[tn][3]);
      lsum += (p0 + p1) + (p2 + p3);
      uint2 pw2; pw2.x = pkbf(p0, p1); pw2.y = pkbf(p2, p3);
      *(uint2*)&Pw[l15 * 72 + tn * 16 + quad * 4] = pw2;
    }

    // O += P·V : 4 fully independent chains (nt), k=32 (one MFMA each)
    bf16x8 pa = *(const bf16x8*)&Pw[l15 * 72 + quad * 8];
#pragma unroll
    for (int nt = 0; nt < 4; nt++) {
      int dv = nt * 16 + l15;
      bf16x8 vb = *(const bf16x8*)&Vc[(dv * 4 + (quad ^ (dv & 3))) * 8];
      oacc[nt] = __builtin_amdgcn_mfma_f32_16x16x32_bf16(pa, vb, oacc[nt], 0, 0, 0);
    }
  }
  __syncthreads();  // all waves done with K/V buffers before overlay

  // reduce lsum over quads (lane's lsum is for q=l15)
  lsum += __shfl_xor(lsum, 16, 64);
  lsum += __shfl_xor(lsum, 32, 64);

  float* OshF = (float*)smem;          // [8][16][68]
  float* lshF = OshF + 8 * 16 * 68;    // [8][16]
  if (lane < 16) lshF[w * 16 + lane] = lsum;
#pragma unroll
  for (int nt = 0; nt < 4; nt++)
#pragma unroll
    for (int r = 0; r < 4; r++)
      OshF[w * 1088 + (quad * 4 + r) * 68 + nt * 16 + l15] = oacc[nt][r];
  __syncthreads();

  // combine the two KV halves, normalize, write concat (bf16)
  const int q = tid >> 3;            // 0..63
  const int dv0 = (tid & 7) * 8;
  const int wa = q >> 4, wb = wa + 4, qr = q & 15;
  const float* pa = &OshF[wa * 1088 + qr * 68 + dv0];
  const float* pb = &OshF[wb * 1088 + qr * 68 + dv0];
  float4 a0 = *(const float4*)pa, a1 = *(const float4*)(pa + 4);
  float4 b0 = *(const float4*)pb, b1 = *(const float4*)(pb + 4);
  float li = 1.0f / (lshF[wa * 16 + qr] + lshF[wb * 16 + qr]);
  union { u16 hh[8]; uint4 u4; } o;
  o.hh[0] = f2bf((a0.x + b0.x) * li); o.hh[1] = f2bf((a0.y + b0.y) * li);
  o.hh[2] = f2bf((a0.z + b0.z) * li); o.hh[3] = f2bf((a0.w + b0.w) * li);
  o.hh[4] = f2bf((a1.x + b1.x) * li); o.hh[5] = f2bf((a1.y + b1.y) * li);
  o.hh[6] = f2bf((a1.z + b1.z) * li); o.hh[7] = f2bf((a1.w + b1.w) * li);
  *(uint4*)&conc[(size_t)(qblk + q) * D_MODEL + h * 64 + dv0] = o.u4;
}

// ---------- output GEMM: 64x64 tile, BK=64, async dbuf, 1 barrier/iter ----------
// 1D grid 512, XCD-swizzled: logical l = (bid%8)*64 + bid/8; l = m*16 + n
// (n fastest). Per-XCD chunk: 4 m-rows x all n -> A 0.5MB + B 2MB < 4MB L2.
__global__ __launch_bounds__(256, 4) void out_gemm_k(
    const u16* __restrict__ A, const u16* __restrict__ Bt,
    const float* __restrict__ bias, float* __restrict__ out) {
  const int bid = blockIdx.x;
  const int l = (bid & 7) * 64 + (bid >> 3);   // bijective: 512 = 8*64
  const int m0 = (l >> 4) * 64, n0 = (l & 15) * 64;
  __shared__ __align__(16) u16 smem[4 * 4096];  // A0 A1 B0 B1 (8KB each)
  const int tid = threadIdx.x;
  const int w = tid >> 6, lane = tid & 63, quad = lane >> 4, l15 = lane & 15;
  const int wm = (w >> 1) * 32, wn = (w & 1) * 32;
  const int pb = w * 128;

  f32x4 acc[2][2] = {};
  {
    u16* As = smem; u16* Bs = smem + 8192;
#pragma unroll
    for (int e = 0; e < 2; e++) {
      int p = pb + e * 64 + lane;
      int r = p >> 3, cg = (p & 7) ^ (r & 7);
      gl16(&A[(size_t)(m0 + r) * D_MODEL + cg * 8], As + (pb + e * 64) * 8);
      gl16(&Bt[(size_t)(n0 + r) * D_MODEL + cg * 8], Bs + (pb + e * 64) * 8);
    }
  }
  for (int it = 0; it < 16; it++) {
    __syncthreads();
    if (it < 15) {
      const int k0 = (it + 1) * 64;
      u16* As = smem + ((it + 1) & 1) * 4096;
      u16* Bs = smem + 8192 + ((it + 1) & 1) * 4096;
#pragma unroll
      for (int e = 0; e < 2; e++) {
        int p = pb + e * 64 + lane;
        int r = p >> 3, cg = (p & 7) ^ (r & 7);
        gl16(&A[(size_t)(m0 + r) * D_MODEL + k0 + cg * 8], As + (pb + e * 64) * 8);
        gl16(&Bt[(size_t)(n0 + r) * D_MODEL + k0 + cg * 8], Bs + (pb + e * 64) * 8);
      }
    }
    const u16* As = smem + (it & 1) * 4096;
    const u16* Bs = smem + 8192 + (it & 1) * 4096;
#pragma unroll
    for (int kc = 0; kc < 2; kc++) {
      const int c = kc * 4 + quad;
      bf16x8 af[2], bfr[2];
#pragma unroll
      for (int t = 0; t < 2; t++) {
        int ma = wm + t * 16 + l15, na = wn + t * 16 + l15;
        af[t] = *(const bf16x8*)&As[(ma * 8 + (c ^ (ma & 7))) * 8];
        bfr[t] = *(const bf16x8*)&Bs[(na * 8 + (c ^ (na & 7))) * 8];
      }
#pragma unroll
      for (int tm = 0; tm < 2; tm++)
#pragma unroll
        for (int tn = 0; tn < 2; tn++)
          acc[tm][tn] = __builtin_amdgcn_mfma_f32_16x16x32_bf16(af[tm], bfr[tn], acc[tm][tn], 0, 0, 0);
    }
  }
#pragma unroll
  for (int tm = 0; tm < 2; tm++)
#pragma unroll
    for (int tn = 0; tn < 2; tn++)
#pragma unroll
      for (int r = 0; r < 4; r++) {
        int row = m0 + wm + tm * 16 + quad * 4 + r;
        int col = n0 + wn + tn * 16 + l15;
        out[(size_t)row * D_MODEL + col] = acc[tm][tn][r] + bias[col];
      }
}

extern "C" void kernel_launch(void* const* d_in, const int* in_sizes, int n_in,
                              void* d_out, int out_size, void* d_ws, size_t ws_size,
                              hipStream_t stream) {
  const float* Q  = (const float*)d_in[0];
  const float* K  = (const float*)d_in[1];
  const float* V  = (const float*)d_in[2];
  const float* Wq = (const float*)d_in[3];
  const float* bq = (const float*)d_in[4];
  const float* Wk = (const float*)d_in[5];
  const float* bk = (const float*)d_in[6];
  const float* Wv = (const float*)d_in[7];
  const float* bv = (const float*)d_in[8];
  const float* Wo = (const float*)d_in[9];
  const float* bo = (const float*)d_in[10];
  float* out = (float*)d_out;

  u16* ws = (u16*)d_ws;
  u16* QKVb = ws;                                   // 3*S*D
  u16* Wqt  = QKVb + (size_t)3 * S_LEN * D_MODEL;   // D*D each
  u16* Wkt  = Wqt + (size_t)D_MODEL * D_MODEL;
  u16* Wvt  = Wkt + (size_t)D_MODEL * D_MODEL;
  u16* Wot  = Wvt + (size_t)D_MODEL * D_MODEL;
  u16* qbuf = Wot + (size_t)D_MODEL * D_MODEL;      // S*D
  u16* kbuf = qbuf + (size_t)S_LEN * D_MODEL;       // S*D
  u16* vTb  = kbuf + (size_t)S_LEN * D_MODEL;       // D*S
  u16* conc = vTb + (size_t)S_LEN * D_MODEL;        // S*D

  prep_k<<<dim3(10240), 256, 0, stream>>>(Q, K, V, Wq, Wk, Wv, Wo,
                                          QKVb, Wqt, Wkt, Wvt, Wot);
  proj_gemm_k<<<dim3(384), 256, 0, stream>>>(
      QKVb, Wqt, Wkt, Wvt, bq, bk, bv, qbuf, kbuf, vTb);
  attn_k<<<dim3(512), 512, 0, stream>>>(qbuf, kbuf, vTb, conc);
  out_gemm_k<<<dim3(512), 256, 0, stream>>>(conc, Wot, bo, out);
}

// Round 2
// 160.913 us; speedup vs baseline: 1.0318x; 1.0295x over previous
//
#include <hip/hip_runtime.h>
#include <stdint.h>

#define S_LEN 2048
#define D_MODEL 1024
#define NH 16
#define DKV 64

typedef unsigned short u16;
typedef __bf16 bf16x8 __attribute__((ext_vector_type(8)));
typedef float f32x4 __attribute__((ext_vector_type(4)));

__device__ __forceinline__ u16 f2bf(float f) {
  union { float f; uint32_t u; } v; v.f = f;
  uint32_t r = v.u + 0x7FFFu + ((v.u >> 16) & 1u);
  return (u16)(r >> 16);
}
// pack two positive floats to bf16x2 (cheap round; softmax-normalized later)
__device__ __forceinline__ uint32_t pkbf(float lo, float hi) {
  union { float f; uint32_t u; } a, b; a.f = lo; b.f = hi;
  return ((b.u + 0x8000u) & 0xFFFF0000u) | ((a.u + 0x8000u) >> 16);
}
// async global->LDS 16B: lds dest is WAVE-UNIFORM base; HW adds lane*16
__device__ __forceinline__ void gl16(const u16* g, u16* l) {
  __builtin_amdgcn_global_load_lds(
      (const __attribute__((address_space(1))) unsigned int*)g,
      (__attribute__((address_space(3))) unsigned int*)l, 16, 0, 0);
}

// ---------- fused preprocessing: conv QKV + transpose Wq/Wk/Wv + transpose Wo ----------
// 1D grid: [0,6144) conv, [6144,9216) qkvw transpose, [9216,10240) Wo transpose
__global__ __launch_bounds__(256) void prep_k(
    const float* __restrict__ Q, const float* __restrict__ K,
    const float* __restrict__ V, const float* __restrict__ Wq,
    const float* __restrict__ Wk, const float* __restrict__ Wv,
    const float* __restrict__ Wo, u16* __restrict__ QKVb,
    u16* __restrict__ Wqt, u16* __restrict__ Wkt, u16* __restrict__ Wvt,
    u16* __restrict__ Wot) {
  __shared__ float tile[32][33];
  const int idx = blockIdx.x;
  if (idx < 6144) {
    const int z = idx >> 11, blk = idx & 2047;
    const float* src = (z == 0) ? Q : (z == 1) ? K : V;
    u16* dst = QKVb + (size_t)z * S_LEN * D_MODEL;
    size_t i = ((size_t)blk * 256 + threadIdx.x) * 4;
    const float4 v = *(const float4*)(src + i);
    union { u16 h[4]; uint2 u2; } o;
    o.h[0] = f2bf(v.x); o.h[1] = f2bf(v.y); o.h[2] = f2bf(v.z); o.h[3] = f2bf(v.w);
    *(uint2*)(dst + i) = o.u2;
    return;
  }
  const float* ip; u16* op; int R, C, r0, c0;
  if (idx < 9216) {
    int t = idx - 6144;
    int which = t >> 10, head = (t & 1023) >> 6, tl = t & 63;
    ip = ((which == 0) ? Wq : (which == 1) ? Wk : Wv) + (size_t)head * D_MODEL * DKV;
    op = ((which == 0) ? Wqt : (which == 1) ? Wkt : Wvt) + (size_t)head * D_MODEL * DKV;
    R = D_MODEL; C = DKV; c0 = (tl & 1) * 32; r0 = (tl >> 1) * 32;
  } else {
    int t = idx - 9216;
    ip = Wo; op = Wot; R = D_MODEL; C = D_MODEL;
    c0 = (t & 31) * 32; r0 = (t >> 5) * 32;
  }
  int tr = threadIdx.x >> 5, tc = threadIdx.x & 31;
#pragma unroll
  for (int i = 0; i < 4; i++)
    tile[tr + i * 8][tc] = ip[(size_t)(r0 + tr + i * 8) * C + c0 + tc];
  __syncthreads();
#pragma unroll
  for (int i = 0; i < 4; i++) {
    int c = tr + i * 8;
    op[(size_t)(c0 + c) * R + r0 + tc] = f2bf(tile[tc][c]);
  }
}

// ---------- projection GEMM m97-style: 128x128 tile, BK=64, async dbuf, 1 barrier/iter ----------
// 1D grid 384, XCD-swizzled: logical l = (bid%8)*48 + bid/8; l = z*128 + m*8 + n
__global__ __launch_bounds__(256, 2) void proj_gemm_k(
    const u16* __restrict__ qkvb, const u16* __restrict__ Wqt,
    const u16* __restrict__ Wkt, const u16* __restrict__ Wvt,
    const float* __restrict__ bq, const float* __restrict__ bk,
    const float* __restrict__ bv,
    u16* __restrict__ qb, u16* __restrict__ kb, u16* __restrict__ vT) {
  const int bid = blockIdx.x;
  const int l = (bid & 7) * 48 + (bid >> 3);   // bijective: 384 = 8*48
  const int z = l >> 7, rem = l & 127;
  const int m0 = (rem >> 3) * 128, n0 = (rem & 7) * 128;
  const u16* A = qkvb + (size_t)z * S_LEN * D_MODEL;
  const u16* Bt = (z == 0) ? Wqt : (z == 1) ? Wkt : Wvt;
  const float* bias = (z == 0) ? bq : (z == 1) ? bk : bv;
  const float scale = (z == 0) ? 0.18033688f : 1.0f;  // (1/8)*log2(e) folded into q

  __shared__ __align__(16) u16 smem[4 * 8192];  // A0 A1 B0 B1 (16KB each)
  const int tid = threadIdx.x;
  const int w = tid >> 6, lane = tid & 63, quad = lane >> 4, l15 = lane & 15;
  const int wm = (w >> 1) * 64, wn = (w & 1) * 64;
  const int pb = w * 256;

  f32x4 acc[4][4] = {};

  {
    u16* As = smem; u16* Bs = smem + 16384;
#pragma unroll
    for (int e = 0; e < 4; e++) {
      int p = pb + e * 64 + lane;
      int r = p >> 3, cg = (p & 7) ^ (r & 7);
      gl16(&A[(size_t)(m0 + r) * D_MODEL + cg * 8], As + (pb + e * 64) * 8);
      gl16(&Bt[(size_t)(n0 + r) * D_MODEL + cg * 8], Bs + (pb + e * 64) * 8);
    }
  }
  for (int it = 0; it < 16; it++) {
    __syncthreads();
    if (it < 15) {
      const int k0 = (it + 1) * 64;
      u16* As = smem + ((it + 1) & 1) * 8192;
      u16* Bs = smem + 16384 + ((it + 1) & 1) * 8192;
#pragma unroll
      for (int e = 0; e < 4; e++) {
        int p = pb + e * 64 + lane;
        int r = p >> 3, cg = (p & 7) ^ (r & 7);
        gl16(&A[(size_t)(m0 + r) * D_MODEL + k0 + cg * 8], As + (pb + e * 64) * 8);
        gl16(&Bt[(size_t)(n0 + r) * D_MODEL + k0 + cg * 8], Bs + (pb + e * 64) * 8);
      }
    }
    const u16* As = smem + (it & 1) * 8192;
    const u16* Bs = smem + 16384 + (it & 1) * 8192;
#pragma unroll
    for (int kc = 0; kc < 2; kc++) {
      bf16x8 af[4], bfr[4];
      const int c = kc * 4 + quad;
#pragma unroll
      for (int t = 0; t < 4; t++) {
        int ma = wm + t * 16 + l15, na = wn + t * 16 + l15;
        af[t] = *(const bf16x8*)&As[(ma * 8 + (c ^ (ma & 7))) * 8];
        bfr[t] = *(const bf16x8*)&Bs[(na * 8 + (c ^ (na & 7))) * 8];
      }
#pragma unroll
      for (int tm = 0; tm < 4; tm++)
#pragma unroll
        for (int tn = 0; tn < 4; tn++)
          acc[tm][tn] = __builtin_amdgcn_mfma_f32_16x16x32_bf16(af[tm], bfr[tn], acc[tm][tn], 0, 0, 0);
    }
  }

  if (z < 2) {
    u16* O = (z == 0) ? qb : kb;
#pragma unroll
    for (int tm = 0; tm < 4; tm++)
#pragma unroll
      for (int tn = 0; tn < 4; tn++)
#pragma unroll
        for (int r = 0; r < 4; r++) {
          int row = m0 + wm + tm * 16 + quad * 4 + r;
          int col = n0 + wn + tn * 16 + l15;
          O[(size_t)row * D_MODEL + col] = f2bf((acc[tm][tn][r] + bias[col]) * scale);
        }
  } else {
#pragma unroll
    for (int tm = 0; tm < 4; tm++)
#pragma unroll
      for (int tn = 0; tn < 4; tn++) {
        int col = n0 + wn + tn * 16 + l15;
        int row0 = m0 + wm + tm * 16 + quad * 4;
        float b = bias[col];
        union { u16 h[4]; uint2 u2; } o;
#pragma unroll
        for (int r = 0; r < 4; r++) o.h[r] = f2bf(acc[tm][tn][r] + b);
        *(uint2*)&vT[(size_t)col * S_LEN + row0] = o.u2;
      }
  }
}

// ---------- attention: 3-buf 2-deep counted-vmcnt pipeline (T4) ----------
// 512 thr = 8 waves = {4 q-subs(16q)} x {2 KV halves}; q-tile 64; t-tile 32/iter, 32 iters.
// Per iter/wave: 2 gl16. Top-of-iter: s_waitcnt vmcnt(2) (buf[it%3] done, it+1's
// loads stay IN FLIGHT across s_barrier) -> no vmcnt(0) drain in main loop.
// Writer targets buf[(it+2)%3] = buf[(it-1)%3]; all its readers passed the barrier.
__global__ __launch_bounds__(512) void attn_k(
    const u16* __restrict__ qb, const u16* __restrict__ kb,
    const u16* __restrict__ vT, u16* __restrict__ conc) {
  const int bid = blockIdx.x;
  const int l = (bid & 7) * 64 + (bid >> 3);   // bijective: 512 = 8*64
  const int h = l >> 5, qblk = (l & 31) * 64;
  const int tid = threadIdx.x;
  const int w = tid >> 6, lane = tid & 63, quad = lane >> 4, l15 = lane & 15;
  const int half = w >> 2, wq = w & 3;
  const int q0 = qblk + wq * 16;

  // u16: K[2 half][3 buf][2048] @0 (24KB), V[2][3][2048] @12288 (24KB),
  //      P[8][1152] @24576 (18KB) -> 67.6KB total, 2 blocks/CU.
  // epilogue overlays @0 as float Osh[8][16][68] + lsh[8][16] (35.3KB)
  __shared__ __align__(16) u16 smem[33792];
  u16* Kh = smem + half * 6144;
  u16* Vh = smem + 12288 + half * 6144;
  u16* Pw = smem + 24576 + w * 1152;

  // Q B-frags (n=q=l15, k=dk=kc*32+quad*8+j); q pre-scaled by (1/8)*log2(e)
  bf16x8 qf[2];
#pragma unroll
  for (int kc = 0; kc < 2; kc++)
    qf[kc] = *(const bf16x8*)&qb[(size_t)(q0 + l15) * D_MODEL + h * 64 + kc * 32 + quad * 8];

  const u16* kbase = kb + (size_t)h * 64;
  const u16* vbase = vT + (size_t)(h * 64) * S_LEN;

  // per-wave staging: 1 K chunk + 1 V chunk per lane per iter
  const int p = wq * 64 + lane;                   // 0..255
  const int kr = p >> 3, kcg = (p & 7) ^ (kr & 7);
  const int vr = p >> 2, vcg = (p & 3) ^ (vr & 3);
  const size_t kgoff = (size_t)kr * D_MODEL + kcg * 8;
  const size_t vgoff = (size_t)vr * S_LEN + vcg * 8;
  const int ldsoff = wq * 64 * 8;                 // wave-uniform dest (HW adds lane*16)

  f32x4 oacc[4] = {};
  float lsum = 0.f;

  {  // prologue: stage it=0 -> buf0, it=1 -> buf1 (program order = vmcnt order)
    const int t0 = half * 1024;
    gl16(kbase + (size_t)t0 * D_MODEL + kgoff, Kh + ldsoff);
    gl16(vbase + t0 + vgoff, Vh + ldsoff);
    const int t1 = t0 + 32;
    gl16(kbase + (size_t)t1 * D_MODEL + kgoff, Kh + 2048 + ldsoff);
    gl16(vbase + t1 + vgoff, Vh + 2048 + ldsoff);
  }

  int rd = 0;  // buf index = it % 3
  for (int it = 0; it < 32; it++) {
    // wait: this wave's loads for buf[rd] retired (allow it+1's 2 in flight)
    if (it < 31) asm volatile("s_waitcnt vmcnt(2)" ::: "memory");
    else         asm volatile("s_waitcnt vmcnt(0)" ::: "memory");
    __builtin_amdgcn_s_barrier();   // now ALL waves' buf[rd] chunks visible
    if (it < 30) {                  // prefetch it+2 into buf[(rd+2)%3]
      const int wr = (rd == 0) ? 2 : rd - 1;
      const int t0n = half * 1024 + (it + 2) * 32;
      gl16(kbase + (size_t)t0n * D_MODEL + kgoff, Kh + wr * 2048 + ldsoff);
      gl16(vbase + t0n + vgoff, Vh + wr * 2048 + ldsoff);
    }
    const u16* Kc = Kh + rd * 2048;
    const u16* Vc = Vh + rd * 2048;

    // Sᵀ = K·Qᵀ : 2 independent chains (tn), depth 2 (kc)
    f32x4 sacc[2] = {};
#pragma unroll
    for (int kc = 0; kc < 2; kc++)
#pragma unroll
      for (int tn = 0; tn < 2; tn++) {
        int rr = tn * 16 + l15;
        bf16x8 ka = *(const bf16x8*)&Kc[(rr * 8 + ((kc * 4 + quad) ^ (rr & 7))) * 8];
        sacc[tn] = __builtin_amdgcn_mfma_f32_16x16x32_bf16(ka, qf[kc], sacc[tn], 0, 0, 0);
      }

    // p = 2^s (log2e folded into q); lane holds Sᵀ[t=tn*16+quad*4+r][q=l15]
#pragma unroll
    for (int tn = 0; tn < 2; tn++) {
      float p0 = exp2f(sacc[tn][0]);
      float p1 = exp2f(sacc[tn][1]);
      float p2 = exp2f(sacc[tn][2]);
      float p3 = exp2f(sacc[tn][3]);
      lsum += (p0 + p1) + (p2 + p3);
      uint2 pw2; pw2.x = pkbf(p0, p1); pw2.y = pkbf(p2, p3);
      *(uint2*)&Pw[l15 * 72 + tn * 16 + quad * 4] = pw2;
    }

    // O += P·V : 4 fully independent chains (nt), k=32 (one MFMA each)
    bf16x8 pa = *(const bf16x8*)&Pw[l15 * 72 + quad * 8];
#pragma unroll
    for (int nt = 0; nt < 4; nt++) {
      int dv = nt * 16 + l15;
      bf16x8 vb = *(const bf16x8*)&Vc[(dv * 4 + (quad ^ (dv & 3))) * 8];
      oacc[nt] = __builtin_amdgcn_mfma_f32_16x16x32_bf16(pa, vb, oacc[nt], 0, 0, 0);
    }
    rd = (rd == 2) ? 0 : rd + 1;
  }
  __syncthreads();  // all waves done with K/V buffers before overlay

  // reduce lsum over quads (lane's lsum is for q=l15)
  lsum += __shfl_xor(lsum, 16, 64);
  lsum += __shfl_xor(lsum, 32, 64);

  float* OshF = (float*)smem;          // [8][16][68]
  float* lshF = OshF + 8 * 16 * 68;    // [8][16]
  if (lane < 16) lshF[w * 16 + lane] = lsum;
#pragma unroll
  for (int nt = 0; nt < 4; nt++)
#pragma unroll
    for (int r = 0; r < 4; r++)
      OshF[w * 1088 + (quad * 4 + r) * 68 + nt * 16 + l15] = oacc[nt][r];
  __syncthreads();

  // combine the two KV halves, normalize, write concat (bf16)
  const int q = tid >> 3;            // 0..63
  const int dv0 = (tid & 7) * 8;
  const int wa = q >> 4, wb = wa + 4, qr = q & 15;
  const float* pa = &OshF[wa * 1088 + qr * 68 + dv0];
  const float* pb = &OshF[wb * 1088 + qr * 68 + dv0];
  float4 a0 = *(const float4*)pa, a1 = *(const float4*)(pa + 4);
  float4 b0 = *(const float4*)pb, b1 = *(const float4*)(pb + 4);
  float li = 1.0f / (lshF[wa * 16 + qr] + lshF[wb * 16 + qr]);
  union { u16 hh[8]; uint4 u4; } o;
  o.hh[0] = f2bf((a0.x + b0.x) * li); o.hh[1] = f2bf((a0.y + b0.y) * li);
  o.hh[2] = f2bf((a0.z + b0.z) * li); o.hh[3] = f2bf((a0.w + b0.w) * li);
  o.hh[4] = f2bf((a1.x + b1.x) * li); o.hh[5] = f2bf((a1.y + b1.y) * li);
  o.hh[6] = f2bf((a1.z + b1.z) * li); o.hh[7] = f2bf((a1.w + b1.w) * li);
  *(uint4*)&conc[(size_t)(qblk + q) * D_MODEL + h * 64 + dv0] = o.u4;
}

// ---------- output GEMM: 64x64 tile, BK=64, 3-buf 2-deep counted-vmcnt ----------
// Per iter/wave: 4 gl16 -> s_waitcnt vmcnt(4) at top keeps it+1's loads in flight.
__global__ __launch_bounds__(256, 2) void out_gemm_k(
    const u16* __restrict__ A, const u16* __restrict__ Bt,
    const float* __restrict__ bias, float* __restrict__ out) {
  const int bid = blockIdx.x;
  const int l = (bid & 7) * 64 + (bid >> 3);   // bijective: 512 = 8*64
  const int m0 = (l >> 4) * 64, n0 = (l & 15) * 64;
  __shared__ __align__(16) u16 smem[6 * 4096];  // A x3 @0, B x3 @12288 (8KB each)
  const int tid = threadIdx.x;
  const int w = tid >> 6, lane = tid & 63, quad = lane >> 4, l15 = lane & 15;
  const int wm = (w >> 1) * 32, wn = (w & 1) * 32;
  const int pb = w * 128;

  f32x4 acc[2][2] = {};
  {  // prologue: k-step 0 -> buf0, k-step 1 -> buf1
#pragma unroll
    for (int e = 0; e < 2; e++) {
      int p = pb + e * 64 + lane;
      int r = p >> 3, cg = (p & 7) ^ (r & 7);
      gl16(&A[(size_t)(m0 + r) * D_MODEL + cg * 8], smem + (pb + e * 64) * 8);
      gl16(&Bt[(size_t)(n0 + r) * D_MODEL + cg * 8], smem + 12288 + (pb + e * 64) * 8);
    }
#pragma unroll
    for (int e = 0; e < 2; e++) {
      int p = pb + e * 64 + lane;
      int r = p >> 3, cg = (p & 7) ^ (r & 7);
      gl16(&A[(size_t)(m0 + r) * D_MODEL + 64 + cg * 8], smem + 4096 + (pb + e * 64) * 8);
      gl16(&Bt[(size_t)(n0 + r) * D_MODEL + 64 + cg * 8], smem + 16384 + (pb + e * 64) * 8);
    }
  }
  int rd = 0;  // buf index = it % 3
  for (int it = 0; it < 16; it++) {
    if (it < 15) asm volatile("s_waitcnt vmcnt(4)" ::: "memory");
    else         asm volatile("s_waitcnt vmcnt(0)" ::: "memory");
    __builtin_amdgcn_s_barrier();
    if (it < 14) {
      const int wr = (rd == 0) ? 2 : rd - 1;
      const int k0 = (it + 2) * 64;
      u16* As = smem + wr * 4096;
      u16* Bs = smem + 12288 + wr * 4096;
#pragma unroll
      for (int e = 0; e < 2; e++) {
        int p = pb + e * 64 + lane;
        int r = p >> 3, cg = (p & 7) ^ (r & 7);
        gl16(&A[(size_t)(m0 + r) * D_MODEL + k0 + cg * 8], As + (pb + e * 64) * 8);
        gl16(&Bt[(size_t)(n0 + r) * D_MODEL + k0 + cg * 8], Bs + (pb + e * 64) * 8);
      }
    }
    const u16* As = smem + rd * 4096;
    const u16* Bs = smem + 12288 + rd * 4096;
#pragma unroll
    for (int kc = 0; kc < 2; kc++) {
      const int c = kc * 4 + quad;
      bf16x8 af[2], bfr[2];
#pragma unroll
      for (int t = 0; t < 2; t++) {
        int ma = wm + t * 16 + l15, na = wn + t * 16 + l15;
        af[t] = *(const bf16x8*)&As[(ma * 8 + (c ^ (ma & 7))) * 8];
        bfr[t] = *(const bf16x8*)&Bs[(na * 8 + (c ^ (na & 7))) * 8];
      }
#pragma unroll
      for (int tm = 0; tm < 2; tm++)
#pragma unroll
        for (int tn = 0; tn < 2; tn++)
          acc[tm][tn] = __builtin_amdgcn_mfma_f32_16x16x32_bf16(af[tm], bfr[tn], acc[tm][tn], 0, 0, 0);
    }
    rd = (rd == 2) ? 0 : rd + 1;
  }
#pragma unroll
  for (int tm = 0; tm < 2; tm++)
#pragma unroll
    for (int tn = 0; tn < 2; tn++)
#pragma unroll
      for (int r = 0; r < 4; r++) {
        int row = m0 + wm + tm * 16 + quad * 4 + r;
        int col = n0 + wn + tn * 16 + l15;
        out[(size_t)row * D_MODEL + col] = acc[tm][tn][r] + bias[col];
      }
}

extern "C" void kernel_launch(void* const* d_in, const int* in_sizes, int n_in,
                              void* d_out, int out_size, void* d_ws, size_t ws_size,
                              hipStream_t stream) {
  const float* Q  = (const float*)d_in[0];
  const float* K  = (const float*)d_in[1];
  const float* V  = (const float*)d_in[2];
  const float* Wq = (const float*)d_in[3];
  const float* bq = (const float*)d_in[4];
  const float* Wk = (const float*)d_in[5];
  const float* bk = (const float*)d_in[6];
  const float* Wv = (const float*)d_in[7];
  const float* bv = (const float*)d_in[8];
  const float* Wo = (const float*)d_in[9];
  const float* bo = (const float*)d_in[10];
  float* out = (float*)d_out;

  u16* ws = (u16*)d_ws;
  u16* QKVb = ws;                                   // 3*S*D
  u16* Wqt  = QKVb + (size_t)3 * S_LEN * D_MODEL;   // D*D each
  u16* Wkt  = Wqt + (size_t)D_MODEL * D_MODEL;
  u16* Wvt  = Wkt + (size_t)D_MODEL * D_MODEL;
  u16* Wot  = Wvt + (size_t)D_MODEL * D_MODEL;
  u16* qbuf = Wot + (size_t)D_MODEL * D_MODEL;      // S*D
  u16* kbuf = qbuf + (size_t)S_LEN * D_MODEL;       // S*D
  u16* vTb  = kbuf + (size_t)S_LEN * D_MODEL;       // D*S
  u16* conc = vTb + (size_t)S_LEN * D_MODEL;        // S*D

  prep_k<<<dim3(10240), 256, 0, stream>>>(Q, K, V, Wq, Wk, Wv, Wo,
                                          QKVb, Wqt, Wkt, Wvt, Wot);
  proj_gemm_k<<<dim3(384), 256, 0, stream>>>(
      QKVb, Wqt, Wkt, Wvt, bq, bk, bv, qbuf, kbuf, vTb);
  attn_k<<<dim3(512), 512, 0, stream>>>(qbuf, kbuf, vTb, conc);
  out_gemm_k<<<dim3(512), 256, 0, stream>>>(conc, Wot, bo, out);
}

// Round 5
// 156.907 us; speedup vs baseline: 1.0582x; 1.0255x over previous
//
#include <hip/hip_runtime.h>
#include <stdint.h>

#define S_LEN 2048
#define D_MODEL 1024
#define NH 16
#define DKV 64

typedef unsigned short u16;
typedef __bf16 bf16x8 __attribute__((ext_vector_type(8)));
typedef float f32x4 __attribute__((ext_vector_type(4)));

__device__ __forceinline__ u16 f2bf(float f) {
  union { float f; uint32_t u; } v; v.f = f;
  uint32_t r = v.u + 0x7FFFu + ((v.u >> 16) & 1u);
  return (u16)(r >> 16);
}
// pack two positive floats to bf16x2 (cheap round; softmax-normalized later)
// NOTE round-3/4 post-mortem: hand-asm v_cvt_pk/v_exp here caused a deterministic
// trans-hazard corruption (compiler can't insert wait-states inside opaque asm).
// Use compiler-known ops only.
__device__ __forceinline__ uint32_t pkbf(float lo, float hi) {
  union { float f; uint32_t u; } a, b; a.f = lo; b.f = hi;
  return ((b.u + 0x8000u) & 0xFFFF0000u) | ((a.u + 0x8000u) >> 16);
}
// async global->LDS 16B: lds dest is WAVE-UNIFORM base; HW adds lane*16
__device__ __forceinline__ void gl16(const u16* g, u16* l) {
  __builtin_amdgcn_global_load_lds(
      (const __attribute__((address_space(1))) unsigned int*)g,
      (__attribute__((address_space(3))) unsigned int*)l, 16, 0, 0);
}

// ---------- fused preprocessing: conv QKV + transpose Wq/Wk/Wv + transpose Wo ----------
// 1D grid: [0,6144) conv, [6144,9216) qkvw transpose, [9216,10240) Wo transpose
__global__ __launch_bounds__(256) void prep_k(
    const float* __restrict__ Q, const float* __restrict__ K,
    const float* __restrict__ V, const float* __restrict__ Wq,
    const float* __restrict__ Wk, const float* __restrict__ Wv,
    const float* __restrict__ Wo, u16* __restrict__ QKVb,
    u16* __restrict__ Wqt, u16* __restrict__ Wkt, u16* __restrict__ Wvt,
    u16* __restrict__ Wot) {
  __shared__ float tile[32][33];
  const int idx = blockIdx.x;
  if (idx < 6144) {
    const int z = idx >> 11, blk = idx & 2047;
    const float* src = (z == 0) ? Q : (z == 1) ? K : V;
    u16* dst = QKVb + (size_t)z * S_LEN * D_MODEL;
    size_t i = ((size_t)blk * 256 + threadIdx.x) * 4;
    const float4 v = *(const float4*)(src + i);
    union { u16 h[4]; uint2 u2; } o;
    o.h[0] = f2bf(v.x); o.h[1] = f2bf(v.y); o.h[2] = f2bf(v.z); o.h[3] = f2bf(v.w);
    *(uint2*)(dst + i) = o.u2;
    return;
  }
  const float* ip; u16* op; int R, C, r0, c0;
  if (idx < 9216) {
    int t = idx - 6144;
    int which = t >> 10, head = (t & 1023) >> 6, tl = t & 63;
    ip = ((which == 0) ? Wq : (which == 1) ? Wk : Wv) + (size_t)head * D_MODEL * DKV;
    op = ((which == 0) ? Wqt : (which == 1) ? Wkt : Wvt) + (size_t)head * D_MODEL * DKV;
    R = D_MODEL; C = DKV; c0 = (tl & 1) * 32; r0 = (tl >> 1) * 32;
  } else {
    int t = idx - 9216;
    ip = Wo; op = Wot; R = D_MODEL; C = D_MODEL;
    c0 = (t & 31) * 32; r0 = (t >> 5) * 32;
  }
  int tr = threadIdx.x >> 5, tc = threadIdx.x & 31;
#pragma unroll
  for (int i = 0; i < 4; i++)
    tile[tr + i * 8][tc] = ip[(size_t)(r0 + tr + i * 8) * C + c0 + tc];
  __syncthreads();
#pragma unroll
  for (int i = 0; i < 4; i++) {
    int c = tr + i * 8;
    op[(size_t)(c0 + c) * R + r0 + tc] = f2bf(tile[tc][c]);
  }
}

// ---------- projection GEMM m97-style: 128x128 tile, BK=64, async dbuf, 1 barrier/iter ----------
// 1D grid 384, XCD-swizzled: logical l = (bid%8)*48 + bid/8; l = z*128 + m*8 + n
__global__ __launch_bounds__(256, 2) void proj_gemm_k(
    const u16* __restrict__ qkvb, const u16* __restrict__ Wqt,
    const u16* __restrict__ Wkt, const u16* __restrict__ Wvt,
    const float* __restrict__ bq, const float* __restrict__ bk,
    const float* __restrict__ bv,
    u16* __restrict__ qb, u16* __restrict__ kb, u16* __restrict__ vT) {
  const int bid = blockIdx.x;
  const int l = (bid & 7) * 48 + (bid >> 3);   // bijective: 384 = 8*48
  const int z = l >> 7, rem = l & 127;
  const int m0 = (rem >> 3) * 128, n0 = (rem & 7) * 128;
  const u16* A = qkvb + (size_t)z * S_LEN * D_MODEL;
  const u16* Bt = (z == 0) ? Wqt : (z == 1) ? Wkt : Wvt;
  const float* bias = (z == 0) ? bq : (z == 1) ? bk : bv;
  const float scale = (z == 0) ? 0.18033688f : 1.0f;  // (1/8)*log2(e) folded into q

  __shared__ __align__(16) u16 smem[4 * 8192];  // A0 A1 B0 B1 (16KB each)
  const int tid = threadIdx.x;
  const int w = tid >> 6, lane = tid & 63, quad = lane >> 4, l15 = lane & 15;
  const int wm = (w >> 1) * 64, wn = (w & 1) * 64;
  const int pb = w * 256;

  f32x4 acc[4][4] = {};

  {
    u16* As = smem; u16* Bs = smem + 16384;
#pragma unroll
    for (int e = 0; e < 4; e++) {
      int p = pb + e * 64 + lane;
      int r = p >> 3, cg = (p & 7) ^ (r & 7);
      gl16(&A[(size_t)(m0 + r) * D_MODEL + cg * 8], As + (pb + e * 64) * 8);
      gl16(&Bt[(size_t)(n0 + r) * D_MODEL + cg * 8], Bs + (pb + e * 64) * 8);
    }
  }
  for (int it = 0; it < 16; it++) {
    __syncthreads();
    if (it < 15) {
      const int k0 = (it + 1) * 64;
      u16* As = smem + ((it + 1) & 1) * 8192;
      u16* Bs = smem + 16384 + ((it + 1) & 1) * 8192;
#pragma unroll
      for (int e = 0; e < 4; e++) {
        int p = pb + e * 64 + lane;
        int r = p >> 3, cg = (p & 7) ^ (r & 7);
        gl16(&A[(size_t)(m0 + r) * D_MODEL + k0 + cg * 8], As + (pb + e * 64) * 8);
        gl16(&Bt[(size_t)(n0 + r) * D_MODEL + k0 + cg * 8], Bs + (pb + e * 64) * 8);
      }
    }
    const u16* As = smem + (it & 1) * 8192;
    const u16* Bs = smem + 16384 + (it & 1) * 8192;
#pragma unroll
    for (int kc = 0; kc < 2; kc++) {
      bf16x8 af[4], bfr[4];
      const int c = kc * 4 + quad;
#pragma unroll
      for (int t = 0; t < 4; t++) {
        int ma = wm + t * 16 + l15, na = wn + t * 16 + l15;
        af[t] = *(const bf16x8*)&As[(ma * 8 + (c ^ (ma & 7))) * 8];
        bfr[t] = *(const bf16x8*)&Bs[(na * 8 + (c ^ (na & 7))) * 8];
      }
#pragma unroll
      for (int tm = 0; tm < 4; tm++)
#pragma unroll
        for (int tn = 0; tn < 4; tn++)
          acc[tm][tn] = __builtin_amdgcn_mfma_f32_16x16x32_bf16(af[tm], bfr[tn], acc[tm][tn], 0, 0, 0);
    }
  }

  if (z < 2) {
    u16* O = (z == 0) ? qb : kb;
#pragma unroll
    for (int tm = 0; tm < 4; tm++)
#pragma unroll
      for (int tn = 0; tn < 4; tn++)
#pragma unroll
        for (int r = 0; r < 4; r++) {
          int row = m0 + wm + tm * 16 + quad * 4 + r;
          int col = n0 + wn + tn * 16 + l15;
          O[(size_t)row * D_MODEL + col] = f2bf((acc[tm][tn][r] + bias[col]) * scale);
        }
  } else {
#pragma unroll
    for (int tm = 0; tm < 4; tm++)
#pragma unroll
      for (int tn = 0; tn < 4; tn++) {
        int col = n0 + wn + tn * 16 + l15;
        int row0 = m0 + wm + tm * 16 + quad * 4;
        float b = bias[col];
        union { u16 h[4]; uint2 u2; } o;
#pragma unroll
        for (int r = 0; r < 4; r++) o.h[r] = f2bf(acc[tm][tn][r] + b);
        *(uint2*)&vT[(size_t)col * S_LEN + row0] = o.u2;
      }
  }
}

// ---------- attention: 3-buf 2-deep counted-vmcnt, FULLY UNROLLED (static rd) ----------
// 512 thr = 8 waves = {4 q-subs(16q)} x {2 KV halves}; q-tile 64; t-tile 32/iter, 32 iters.
// sched_barrier(0) after each raw s_barrier pins memory ops below it (rule #18 family).
// exp2 via __builtin_amdgcn_exp2f (compiler-known -> trans-hazard handled; skips ocml
// denormal fixup). Pack via pkbf (compiler-known ALU ops).
__global__ __launch_bounds__(512) void attn_k(
    const u16* __restrict__ qb, const u16* __restrict__ kb,
    const u16* __restrict__ vT, u16* __restrict__ conc) {
  const int bid = blockIdx.x;
  const int l = (bid & 7) * 64 + (bid >> 3);   // bijective: 512 = 8*64
  const int h = l >> 5, qblk = (l & 31) * 64;
  const int tid = threadIdx.x;
  const int w = tid >> 6, lane = tid & 63, quad = lane >> 4, l15 = lane & 15;
  const int half = w >> 2, wq = w & 3;
  const int q0 = qblk + wq * 16;

  // u16: K[2 half][3 buf][2048] @0 (24KB), V[2][3][2048] @12288 (24KB),
  //      P[8][1152] @24576 (18KB) -> 67.6KB total, 2 blocks/CU.
  // epilogue overlays @0 as float Osh[8][16][68] + lsh[8][16] (35.3KB)
  __shared__ __align__(16) u16 smem[33792];
  u16* Kh = smem + half * 6144;
  u16* Vh = smem + 12288 + half * 6144;
  u16* Pw = smem + 24576 + w * 1152;

  // Q B-frags (n=q=l15, k=dk=kc*32+quad*8+j); q pre-scaled by (1/8)*log2(e)
  bf16x8 qf[2];
#pragma unroll
  for (int kc = 0; kc < 2; kc++)
    qf[kc] = *(const bf16x8*)&qb[(size_t)(q0 + l15) * D_MODEL + h * 64 + kc * 32 + quad * 8];

  const u16* kbase = kb + (size_t)h * 64;
  const u16* vbase = vT + (size_t)(h * 64) * S_LEN;

  // per-wave staging: 1 K chunk + 1 V chunk per lane per iter
  const int p = wq * 64 + lane;                   // 0..255
  const int kr = p >> 3, kcg = (p & 7) ^ (kr & 7);
  const int vr = p >> 2, vcg = (p & 3) ^ (vr & 3);
  const size_t kgoff = (size_t)kr * D_MODEL + kcg * 8;
  const size_t vgoff = (size_t)vr * S_LEN + vcg * 8;
  const int ldsoff = wq * 64 * 8;                 // wave-uniform dest (HW adds lane*16)

  f32x4 oacc[4] = {};
  float lsum = 0.f;

  {  // prologue: stage it=0 -> buf0, it=1 -> buf1 (program order = vmcnt order)
    const int t0 = half * 1024;
    gl16(kbase + (size_t)t0 * D_MODEL + kgoff, Kh + ldsoff);
    gl16(vbase + t0 + vgoff, Vh + ldsoff);
    const int t1 = t0 + 32;
    gl16(kbase + (size_t)t1 * D_MODEL + kgoff, Kh + 2048 + ldsoff);
    gl16(vbase + t1 + vgoff, Vh + 2048 + ldsoff);
  }

#pragma unroll
  for (int it = 0; it < 32; it++) {
    const int rd = it % 3;  // compile-time constant after full unroll
    // wait: this wave's loads for buf[rd] retired (allow it+1's 2 in flight)
    if (it < 31) asm volatile("s_waitcnt vmcnt(2)" ::: "memory");
    else         asm volatile("s_waitcnt vmcnt(0)" ::: "memory");
    __builtin_amdgcn_s_barrier();   // now ALL waves' buf[rd] chunks visible
    __builtin_amdgcn_sched_barrier(0);  // pin: nothing (esp. ds_read/gl16) above barrier
    if (it < 30) {                  // prefetch it+2 into buf[(rd+2)%3]
      const int wr = (rd + 2) % 3;
      const int t0n = half * 1024 + (it + 2) * 32;
      gl16(kbase + (size_t)t0n * D_MODEL + kgoff, Kh + wr * 2048 + ldsoff);
      gl16(vbase + t0n + vgoff, Vh + wr * 2048 + ldsoff);
    }
    const u16* Kc = Kh + rd * 2048;
    const u16* Vc = Vh + rd * 2048;

    // Sᵀ = K·Qᵀ : 2 independent chains (tn), depth 2 (kc)
    f32x4 sacc[2] = {};
    __builtin_amdgcn_s_setprio(1);
#pragma unroll
    for (int kc = 0; kc < 2; kc++)
#pragma unroll
      for (int tn = 0; tn < 2; tn++) {
        int rr = tn * 16 + l15;
        bf16x8 ka = *(const bf16x8*)&Kc[(rr * 8 + ((kc * 4 + quad) ^ (rr & 7))) * 8];
        sacc[tn] = __builtin_amdgcn_mfma_f32_16x16x32_bf16(ka, qf[kc], sacc[tn], 0, 0, 0);
      }
    __builtin_amdgcn_s_setprio(0);

    // p = 2^s (log2e folded into q); lane holds Sᵀ[t=tn*16+quad*4+r][q=l15]
#pragma unroll
    for (int tn = 0; tn < 2; tn++) {
      float p0 = __builtin_amdgcn_exp2f(sacc[tn][0]);
      float p1 = __builtin_amdgcn_exp2f(sacc[tn][1]);
      float p2 = __builtin_amdgcn_exp2f(sacc[tn][2]);
      float p3 = __builtin_amdgcn_exp2f(sacc[tn][3]);
      lsum += (p0 + p1) + (p2 + p3);
      uint2 pw2; pw2.x = pkbf(p0, p1); pw2.y = pkbf(p2, p3);
      *(uint2*)&Pw[l15 * 72 + tn * 16 + quad * 4] = pw2;
    }

    // O += P·V : 4 fully independent chains (nt), k=32 (one MFMA each)
    bf16x8 pa = *(const bf16x8*)&Pw[l15 * 72 + quad * 8];
    __builtin_amdgcn_s_setprio(1);
#pragma unroll
    for (int nt = 0; nt < 4; nt++) {
      int dv = nt * 16 + l15;
      bf16x8 vb = *(const bf16x8*)&Vc[(dv * 4 + (quad ^ (dv & 3))) * 8];
      oacc[nt] = __builtin_amdgcn_mfma_f32_16x16x32_bf16(pa, vb, oacc[nt], 0, 0, 0);
    }
    __builtin_amdgcn_s_setprio(0);
  }
  __syncthreads();  // all waves done with K/V buffers before overlay

  // reduce lsum over quads (lane's lsum is for q=l15)
  lsum += __shfl_xor(lsum, 16, 64);
  lsum += __shfl_xor(lsum, 32, 64);

  float* OshF = (float*)smem;          // [8][16][68]
  float* lshF = OshF + 8 * 16 * 68;    // [8][16]
  if (lane < 16) lshF[w * 16 + lane] = lsum;
#pragma unroll
  for (int nt = 0; nt < 4; nt++)
#pragma unroll
    for (int r = 0; r < 4; r++)
      OshF[w * 1088 + (quad * 4 + r) * 68 + nt * 16 + l15] = oacc[nt][r];
  __syncthreads();

  // combine the two KV halves, normalize, write concat (bf16)
  const int q = tid >> 3;            // 0..63
  const int dv0 = (tid & 7) * 8;
  const int wa = q >> 4, wb = wa + 4, qr = q & 15;
  const float* pa = &OshF[wa * 1088 + qr * 68 + dv0];
  const float* pb = &OshF[wb * 1088 + qr * 68 + dv0];
  float4 a0 = *(const float4*)pa, a1 = *(const float4*)(pa + 4);
  float4 b0 = *(const float4*)pb, b1 = *(const float4*)(pb + 4);
  float li = 1.0f / (lshF[wa * 16 + qr] + lshF[wb * 16 + qr]);
  union { u16 hh[8]; uint4 u4; } o;
  o.hh[0] = f2bf((a0.x + b0.x) * li); o.hh[1] = f2bf((a0.y + b0.y) * li);
  o.hh[2] = f2bf((a0.z + b0.z) * li); o.hh[3] = f2bf((a0.w + b0.w) * li);
  o.hh[4] = f2bf((a1.x + b1.x) * li); o.hh[5] = f2bf((a1.y + b1.y) * li);
  o.hh[6] = f2bf((a1.z + b1.z) * li); o.hh[7] = f2bf((a1.w + b1.w) * li);
  *(uint4*)&conc[(size_t)(qblk + q) * D_MODEL + h * 64 + dv0] = o.u4;
}

// ---------- output GEMM: 64x64 tile, BK=64, 3-buf 2-deep counted-vmcnt ----------
// Per iter/wave: 4 gl16 -> s_waitcnt vmcnt(4) at top keeps it+1's loads in flight.
// sched_barrier(0)-after-s_barrier pins the schedule.
__global__ __launch_bounds__(256, 2) void out_gemm_k(
    const u16* __restrict__ A, const u16* __restrict__ Bt,
    const float* __restrict__ bias, float* __restrict__ out) {
  const int bid = blockIdx.x;
  const int l = (bid & 7) * 64 + (bid >> 3);   // bijective: 512 = 8*64
  const int m0 = (l >> 4) * 64, n0 = (l & 15) * 64;
  __shared__ __align__(16) u16 smem[6 * 4096];  // A x3 @0, B x3 @12288 (8KB each)
  const int tid = threadIdx.x;
  const int w = tid >> 6, lane = tid & 63, quad = lane >> 4, l15 = lane & 15;
  const int wm = (w >> 1) * 32, wn = (w & 1) * 32;
  const int pb = w * 128;

  f32x4 acc[2][2] = {};
  {  // prologue: k-step 0 -> buf0, k-step 1 -> buf1
#pragma unroll
    for (int e = 0; e < 2; e++) {
      int p = pb + e * 64 + lane;
      int r = p >> 3, cg = (p & 7) ^ (r & 7);
      gl16(&A[(size_t)(m0 + r) * D_MODEL + cg * 8], smem + (pb + e * 64) * 8);
      gl16(&Bt[(size_t)(n0 + r) * D_MODEL + cg * 8], smem + 12288 + (pb + e * 64) * 8);
    }
#pragma unroll
    for (int e = 0; e < 2; e++) {
      int p = pb + e * 64 + lane;
      int r = p >> 3, cg = (p & 7) ^ (r & 7);
      gl16(&A[(size_t)(m0 + r) * D_MODEL + 64 + cg * 8], smem + 4096 + (pb + e * 64) * 8);
      gl16(&Bt[(size_t)(n0 + r) * D_MODEL + 64 + cg * 8], smem + 16384 + (pb + e * 64) * 8);
    }
  }
#pragma unroll
  for (int it = 0; it < 16; it++) {
    const int rd = it % 3;  // compile-time constant after full unroll
    if (it < 15) asm volatile("s_waitcnt vmcnt(4)" ::: "memory");
    else         asm volatile("s_waitcnt vmcnt(0)" ::: "memory");
    __builtin_amdgcn_s_barrier();
    __builtin_amdgcn_sched_barrier(0);  // pin: nothing above barrier
    if (it < 14) {
      const int wr = (rd + 2) % 3;
      const int k0 = (it + 2) * 64;
      u16* As = smem + wr * 4096;
      u16* Bs = smem + 12288 + wr * 4096;
#pragma unroll
      for (int e = 0; e < 2; e++) {
        int p = pb + e * 64 + lane;
        int r = p >> 3, cg = (p & 7) ^ (r & 7);
        gl16(&A[(size_t)(m0 + r) * D_MODEL + k0 + cg * 8], As + (pb + e * 64) * 8);
        gl16(&Bt[(size_t)(n0 + r) * D_MODEL + k0 + cg * 8], Bs + (pb + e * 64) * 8);
      }
    }
    const u16* As = smem + rd * 4096;
    const u16* Bs = smem + 12288 + rd * 4096;
#pragma unroll
    for (int kc = 0; kc < 2; kc++) {
      const int c = kc * 4 + quad;
      bf16x8 af[2], bfr[2];
#pragma unroll
      for (int t = 0; t < 2; t++) {
        int ma = wm + t * 16 + l15, na = wn + t * 16 + l15;
        af[t] = *(const bf16x8*)&As[(ma * 8 + (c ^ (ma & 7))) * 8];
        bfr[t] = *(const bf16x8*)&Bs[(na * 8 + (c ^ (na & 7))) * 8];
      }
      __builtin_amdgcn_s_setprio(1);
#pragma unroll
      for (int tm = 0; tm < 2; tm++)
#pragma unroll
        for (int tn = 0; tn < 2; tn++)
          acc[tm][tn] = __builtin_amdgcn_mfma_f32_16x16x32_bf16(af[tm], bfr[tn], acc[tm][tn], 0, 0, 0);
      __builtin_amdgcn_s_setprio(0);
    }
  }
#pragma unroll
  for (int tm = 0; tm < 2; tm++)
#pragma unroll
    for (int tn = 0; tn < 2; tn++)
#pragma unroll
      for (int r = 0; r < 4; r++) {
        int row = m0 + wm + tm * 16 + quad * 4 + r;
        int col = n0 + wn + tn * 16 + l15;
        out[(size_t)row * D_MODEL + col] = acc[tm][tn][r] + bias[col];
      }
}

extern "C" void kernel_launch(void* const* d_in, const int* in_sizes, int n_in,
                              void* d_out, int out_size, void* d_ws, size_t ws_size,
                              hipStream_t stream) {
  const float* Q  = (const float*)d_in[0];
  const float* K  = (const float*)d_in[1];
  const float* V  = (const float*)d_in[2];
  const float* Wq = (const float*)d_in[3];
  const float* bq = (const float*)d_in[4];
  const float* Wk = (const float*)d_in[5];
  const float* bk = (const float*)d_in[6];
  const float* Wv = (const float*)d_in[7];
  const float* bv = (const float*)d_in[8];
  const float* Wo = (const float*)d_in[9];
  const float* bo = (const float*)d_in[10];
  float* out = (float*)d_out;

  u16* ws = (u16*)d_ws;
  u16* QKVb = ws;                                   // 3*S*D
  u16* Wqt  = QKVb + (size_t)3 * S_LEN * D_MODEL;   // D*D each
  u16* Wkt  = Wqt + (size_t)D_MODEL * D_MODEL;
  u16* Wvt  = Wkt + (size_t)D_MODEL * D_MODEL;
  u16* Wot  = Wvt + (size_t)D_MODEL * D_MODEL;
  u16* qbuf = Wot + (size_t)D_MODEL * D_MODEL;      // S*D
  u16* kbuf = qbuf + (size_t)S_LEN * D_MODEL;       // S*D
  u16* vTb  = kbuf + (size_t)S_LEN * D_MODEL;       // D*S
  u16* conc = vTb + (size_t)S_LEN * D_MODEL;        // S*D

  prep_k<<<dim3(10240), 256, 0, stream>>>(Q, K, V, Wq, Wk, Wv, Wo,
                                          QKVb, Wqt, Wkt, Wvt, Wot);
  proj_gemm_k<<<dim3(384), 256, 0, stream>>>(
      QKVb, Wqt, Wkt, Wvt, bq, bk, bv, qbuf, kbuf, vTb);
  attn_k<<<dim3(512), 512, 0, stream>>>(qbuf, kbuf, vTb, conc);
  out_gemm_k<<<dim3(512), 256, 0, stream>>>(conc, Wot, bo, out);
}

// Round 6
// 156.301 us; speedup vs baseline: 1.0623x; 1.0039x over previous
//
#include <hip/hip_runtime.h>
#include <stdint.h>

#define S_LEN 2048
#define D_MODEL 1024
#define NH 16
#define DKV 64

typedef unsigned short u16;
typedef __bf16 bf16x8 __attribute__((ext_vector_type(8)));
typedef float f32x4 __attribute__((ext_vector_type(4)));

__device__ __forceinline__ u16 f2bf(float f) {
  union { float f; uint32_t u; } v; v.f = f;
  uint32_t r = v.u + 0x7FFFu + ((v.u >> 16) & 1u);
  return (u16)(r >> 16);
}
// pack two positive floats to bf16x2 (cheap round; softmax-normalized later)
// NOTE round-3/4 post-mortem: hand-asm v_cvt_pk/v_exp here caused a deterministic
// trans-hazard corruption (compiler can't insert wait-states inside opaque asm).
// Use compiler-known ops only.
__device__ __forceinline__ uint32_t pkbf(float lo, float hi) {
  union { float f; uint32_t u; } a, b; a.f = lo; b.f = hi;
  return ((b.u + 0x8000u) & 0xFFFF0000u) | ((a.u + 0x8000u) >> 16);
}
// async global->LDS 16B: lds dest is WAVE-UNIFORM base; HW adds lane*16
__device__ __forceinline__ void gl16(const u16* g, u16* l) {
  __builtin_amdgcn_global_load_lds(
      (const __attribute__((address_space(1))) unsigned int*)g,
      (__attribute__((address_space(3))) unsigned int*)l, 16, 0, 0);
}

// ---------- fused preprocessing: conv QKV + transpose Wq/Wk/Wv + transpose Wo ----------
// 1D grid: [0,6144) conv, [6144,9216) qkvw transpose, [9216,10240) Wo transpose
__global__ __launch_bounds__(256) void prep_k(
    const float* __restrict__ Q, const float* __restrict__ K,
    const float* __restrict__ V, const float* __restrict__ Wq,
    const float* __restrict__ Wk, const float* __restrict__ Wv,
    const float* __restrict__ Wo, u16* __restrict__ QKVb,
    u16* __restrict__ Wqt, u16* __restrict__ Wkt, u16* __restrict__ Wvt,
    u16* __restrict__ Wot) {
  __shared__ float tile[32][33];
  const int idx = blockIdx.x;
  if (idx < 6144) {
    const int z = idx >> 11, blk = idx & 2047;
    const float* src = (z == 0) ? Q : (z == 1) ? K : V;
    u16* dst = QKVb + (size_t)z * S_LEN * D_MODEL;
    size_t i = ((size_t)blk * 256 + threadIdx.x) * 4;
    const float4 v = *(const float4*)(src + i);
    union { u16 h[4]; uint2 u2; } o;
    o.h[0] = f2bf(v.x); o.h[1] = f2bf(v.y); o.h[2] = f2bf(v.z); o.h[3] = f2bf(v.w);
    *(uint2*)(dst + i) = o.u2;
    return;
  }
  const float* ip; u16* op; int R, C, r0, c0;
  if (idx < 9216) {
    int t = idx - 6144;
    int which = t >> 10, head = (t & 1023) >> 6, tl = t & 63;
    ip = ((which == 0) ? Wq : (which == 1) ? Wk : Wv) + (size_t)head * D_MODEL * DKV;
    op = ((which == 0) ? Wqt : (which == 1) ? Wkt : Wvt) + (size_t)head * D_MODEL * DKV;
    R = D_MODEL; C = DKV; c0 = (tl & 1) * 32; r0 = (tl >> 1) * 32;
  } else {
    int t = idx - 9216;
    ip = Wo; op = Wot; R = D_MODEL; C = D_MODEL;
    c0 = (t & 31) * 32; r0 = (t >> 5) * 32;
  }
  int tr = threadIdx.x >> 5, tc = threadIdx.x & 31;
#pragma unroll
  for (int i = 0; i < 4; i++)
    tile[tr + i * 8][tc] = ip[(size_t)(r0 + tr + i * 8) * C + c0 + tc];
  __syncthreads();
#pragma unroll
  for (int i = 0; i < 4; i++) {
    int c = tr + i * 8;
    op[(size_t)(c0 + c) * R + r0 + tc] = f2bf(tile[tc][c]);
  }
}

// ---------- projection GEMM: 128x64 tile, BK=64, 3-buf 2-deep counted-vmcnt ----------
// Grid 768 = 3 blocks/CU exactly (fixes the 384@2-per-CU 75% balance ceiling).
// XCD-swizzled: l = (bid%8)*96 + bid/8; l = z*256 + m*16 + n (n fastest).
// Per-XCD chunk: one z, 6 m-panels x all n -> A 1.5MB + B 2MB < 4MB L2.
// Per iter/wave: 4 A-gl16 + 2 B-gl16 -> vmcnt(6) at top keeps next iter's in flight.
__global__ __launch_bounds__(256, 2) void proj_gemm_k(
    const u16* __restrict__ qkvb, const u16* __restrict__ Wqt,
    const u16* __restrict__ Wkt, const u16* __restrict__ Wvt,
    const float* __restrict__ bq, const float* __restrict__ bk,
    const float* __restrict__ bv,
    u16* __restrict__ qb, u16* __restrict__ kb, u16* __restrict__ vT) {
  const int bid = blockIdx.x;
  const int l = (bid & 7) * 96 + (bid >> 3);   // bijective: 768 = 8*96
  const int z = l >> 8, rem = l & 255;
  const int m0 = (rem >> 4) * 128, n0 = (rem & 15) * 64;
  const u16* A = qkvb + (size_t)z * S_LEN * D_MODEL;
  const u16* Bt = (z == 0) ? Wqt : (z == 1) ? Wkt : Wvt;
  const float* bias = (z == 0) ? bq : (z == 1) ? bk : bv;
  const float scale = (z == 0) ? 0.18033688f : 1.0f;  // (1/8)*log2(e) folded into q

  // u16: A x3 bufs @0 (16KB each), B x3 bufs @24576 (8KB each) -> 72KB, 2 blocks/CU
  __shared__ __align__(16) u16 smem[36864];
  const int tid = threadIdx.x;
  const int w = tid >> 6, lane = tid & 63, quad = lane >> 4, l15 = lane & 15;
  const int wm = (w >> 1) * 64, wn = (w & 1) * 32;
  const int pbA = w * 256, pbB = w * 128;

  f32x4 acc[4][2] = {};

  {  // prologue: k-step 0 -> buf0, k-step 1 -> buf1 (program order = vmcnt order)
#pragma unroll
    for (int b = 0; b < 2; b++) {
      const int k0 = b * 64;
      u16* As = smem + b * 8192;
      u16* Bs = smem + 24576 + b * 4096;
#pragma unroll
      for (int e = 0; e < 4; e++) {
        int p = pbA + e * 64 + lane;
        int r = p >> 3, cg = (p & 7) ^ (r & 7);
        gl16(&A[(size_t)(m0 + r) * D_MODEL + k0 + cg * 8], As + (pbA + e * 64) * 8);
      }
#pragma unroll
      for (int e = 0; e < 2; e++) {
        int p = pbB + e * 64 + lane;
        int r = p >> 3, cg = (p & 7) ^ (r & 7);
        gl16(&Bt[(size_t)(n0 + r) * D_MODEL + k0 + cg * 8], Bs + (pbB + e * 64) * 8);
      }
    }
  }
#pragma unroll
  for (int it = 0; it < 16; it++) {
    const int rd = it % 3;  // compile-time constant after full unroll
    if (it < 15) asm volatile("s_waitcnt vmcnt(6)" ::: "memory");
    else         asm volatile("s_waitcnt vmcnt(0)" ::: "memory");
    __builtin_amdgcn_s_barrier();
    __builtin_amdgcn_sched_barrier(0);  // pin: nothing (esp. ds_read/gl16) above barrier
    if (it < 14) {
      const int wr = (rd + 2) % 3;
      const int k0 = (it + 2) * 64;
      u16* As = smem + wr * 8192;
      u16* Bs = smem + 24576 + wr * 4096;
#pragma unroll
      for (int e = 0; e < 4; e++) {
        int p = pbA + e * 64 + lane;
        int r = p >> 3, cg = (p & 7) ^ (r & 7);
        gl16(&A[(size_t)(m0 + r) * D_MODEL + k0 + cg * 8], As + (pbA + e * 64) * 8);
      }
#pragma unroll
      for (int e = 0; e < 2; e++) {
        int p = pbB + e * 64 + lane;
        int r = p >> 3, cg = (p & 7) ^ (r & 7);
        gl16(&Bt[(size_t)(n0 + r) * D_MODEL + k0 + cg * 8], Bs + (pbB + e * 64) * 8);
      }
    }
    const u16* As = smem + rd * 8192;
    const u16* Bs = smem + 24576 + rd * 4096;
#pragma unroll
    for (int kc = 0; kc < 2; kc++) {
      bf16x8 af[4], bfr[2];
      const int c = kc * 4 + quad;
#pragma unroll
      for (int t = 0; t < 4; t++) {
        int ma = wm + t * 16 + l15;
        af[t] = *(const bf16x8*)&As[(ma * 8 + (c ^ (ma & 7))) * 8];
      }
#pragma unroll
      for (int t = 0; t < 2; t++) {
        int na = wn + t * 16 + l15;
        bfr[t] = *(const bf16x8*)&Bs[(na * 8 + (c ^ (na & 7))) * 8];
      }
      __builtin_amdgcn_s_setprio(1);
#pragma unroll
      for (int tm = 0; tm < 4; tm++)
#pragma unroll
        for (int tn = 0; tn < 2; tn++)
          acc[tm][tn] = __builtin_amdgcn_mfma_f32_16x16x32_bf16(af[tm], bfr[tn], acc[tm][tn], 0, 0, 0);
      __builtin_amdgcn_s_setprio(0);
    }
  }

  if (z < 2) {
    u16* O = (z == 0) ? qb : kb;
#pragma unroll
    for (int tm = 0; tm < 4; tm++)
#pragma unroll
      for (int tn = 0; tn < 2; tn++)
#pragma unroll
        for (int r = 0; r < 4; r++) {
          int row = m0 + wm + tm * 16 + quad * 4 + r;
          int col = n0 + wn + tn * 16 + l15;
          O[(size_t)row * D_MODEL + col] = f2bf((acc[tm][tn][r] + bias[col]) * scale);
        }
  } else {
#pragma unroll
    for (int tm = 0; tm < 4; tm++)
#pragma unroll
      for (int tn = 0; tn < 2; tn++) {
        int col = n0 + wn + tn * 16 + l15;
        int row0 = m0 + wm + tm * 16 + quad * 4;
        float b = bias[col];
        union { u16 h[4]; uint2 u2; } o;
#pragma unroll
        for (int r = 0; r < 4; r++) o.h[r] = f2bf(acc[tm][tn][r] + b);
        *(uint2*)&vT[(size_t)col * S_LEN + row0] = o.u2;
      }
  }
}

// ---------- attention: 3-buf 2-deep counted-vmcnt, FULLY UNROLLED (static rd) ----------
// 512 thr = 8 waves = {4 q-subs(16q)} x {2 KV halves}; q-tile 64; t-tile 32/iter, 32 iters.
// sched_barrier(0) after each raw s_barrier pins memory ops below it (rule #18 family).
// exp2 via __builtin_amdgcn_exp2f (compiler-known -> trans-hazard handled; skips ocml
// denormal fixup). Pack via pkbf (compiler-known ALU ops).
__global__ __launch_bounds__(512) void attn_k(
    const u16* __restrict__ qb, const u16* __restrict__ kb,
    const u16* __restrict__ vT, u16* __restrict__ conc) {
  const int bid = blockIdx.x;
  const int l = (bid & 7) * 64 + (bid >> 3);   // bijective: 512 = 8*64
  const int h = l >> 5, qblk = (l & 31) * 64;
  const int tid = threadIdx.x;
  const int w = tid >> 6, lane = tid & 63, quad = lane >> 4, l15 = lane & 15;
  const int half = w >> 2, wq = w & 3;
  const int q0 = qblk + wq * 16;

  // u16: K[2 half][3 buf][2048] @0 (24KB), V[2][3][2048] @12288 (24KB),
  //      P[8][1152] @24576 (18KB) -> 67.6KB total, 2 blocks/CU.
  // epilogue overlays @0 as float Osh[8][16][68] + lsh[8][16] (35.3KB)
  __shared__ __align__(16) u16 smem[33792];
  u16* Kh = smem + half * 6144;
  u16* Vh = smem + 12288 + half * 6144;
  u16* Pw = smem + 24576 + w * 1152;

  // Q B-frags (n=q=l15, k=dk=kc*32+quad*8+j); q pre-scaled by (1/8)*log2(e)
  bf16x8 qf[2];
#pragma unroll
  for (int kc = 0; kc < 2; kc++)
    qf[kc] = *(const bf16x8*)&qb[(size_t)(q0 + l15) * D_MODEL + h * 64 + kc * 32 + quad * 8];

  const u16* kbase = kb + (size_t)h * 64;
  const u16* vbase = vT + (size_t)(h * 64) * S_LEN;

  // per-wave staging: 1 K chunk + 1 V chunk per lane per iter
  const int p = wq * 64 + lane;                   // 0..255
  const int kr = p >> 3, kcg = (p & 7) ^ (kr & 7);
  const int vr = p >> 2, vcg = (p & 3) ^ (vr & 3);
  const size_t kgoff = (size_t)kr * D_MODEL + kcg * 8;
  const size_t vgoff = (size_t)vr * S_LEN + vcg * 8;
  const int ldsoff = wq * 64 * 8;                 // wave-uniform dest (HW adds lane*16)

  f32x4 oacc[4] = {};
  float lsum = 0.f;

  {  // prologue: stage it=0 -> buf0, it=1 -> buf1 (program order = vmcnt order)
    const int t0 = half * 1024;
    gl16(kbase + (size_t)t0 * D_MODEL + kgoff, Kh + ldsoff);
    gl16(vbase + t0 + vgoff, Vh + ldsoff);
    const int t1 = t0 + 32;
    gl16(kbase + (size_t)t1 * D_MODEL + kgoff, Kh + 2048 + ldsoff);
    gl16(vbase + t1 + vgoff, Vh + 2048 + ldsoff);
  }

#pragma unroll
  for (int it = 0; it < 32; it++) {
    const int rd = it % 3;  // compile-time constant after full unroll
    // wait: this wave's loads for buf[rd] retired (allow it+1's 2 in flight)
    if (it < 31) asm volatile("s_waitcnt vmcnt(2)" ::: "memory");
    else         asm volatile("s_waitcnt vmcnt(0)" ::: "memory");
    __builtin_amdgcn_s_barrier();   // now ALL waves' buf[rd] chunks visible
    __builtin_amdgcn_sched_barrier(0);  // pin: nothing (esp. ds_read/gl16) above barrier
    if (it < 30) {                  // prefetch it+2 into buf[(rd+2)%3]
      const int wr = (rd + 2) % 3;
      const int t0n = half * 1024 + (it + 2) * 32;
      gl16(kbase + (size_t)t0n * D_MODEL + kgoff, Kh + wr * 2048 + ldsoff);
      gl16(vbase + t0n + vgoff, Vh + wr * 2048 + ldsoff);
    }
    const u16* Kc = Kh + rd * 2048;
    const u16* Vc = Vh + rd * 2048;

    // Sᵀ = K·Qᵀ : 2 independent chains (tn), depth 2 (kc)
    f32x4 sacc[2] = {};
    __builtin_amdgcn_s_setprio(1);
#pragma unroll
    for (int kc = 0; kc < 2; kc++)
#pragma unroll
      for (int tn = 0; tn < 2; tn++) {
        int rr = tn * 16 + l15;
        bf16x8 ka = *(const bf16x8*)&Kc[(rr * 8 + ((kc * 4 + quad) ^ (rr & 7))) * 8];
        sacc[tn] = __builtin_amdgcn_mfma_f32_16x16x32_bf16(ka, qf[kc], sacc[tn], 0, 0, 0);
      }
    __builtin_amdgcn_s_setprio(0);

    // p = 2^s (log2e folded into q); lane holds Sᵀ[t=tn*16+quad*4+r][q=l15]
#pragma unroll
    for (int tn = 0; tn < 2; tn++) {
      float p0 = __builtin_amdgcn_exp2f(sacc[tn][0]);
      float p1 = __builtin_amdgcn_exp2f(sacc[tn][1]);
      float p2 = __builtin_amdgcn_exp2f(sacc[tn][2]);
      float p3 = __builtin_amdgcn_exp2f(sacc[tn][3]);
      lsum += (p0 + p1) + (p2 + p3);
      uint2 pw2; pw2.x = pkbf(p0, p1); pw2.y = pkbf(p2, p3);
      *(uint2*)&Pw[l15 * 72 + tn * 16 + quad * 4] = pw2;
    }

    // O += P·V : 4 fully independent chains (nt), k=32 (one MFMA each)
    bf16x8 pa = *(const bf16x8*)&Pw[l15 * 72 + quad * 8];
    __builtin_amdgcn_s_setprio(1);
#pragma unroll
    for (int nt = 0; nt < 4; nt++) {
      int dv = nt * 16 + l15;
      bf16x8 vb = *(const bf16x8*)&Vc[(dv * 4 + (quad ^ (dv & 3))) * 8];
      oacc[nt] = __builtin_amdgcn_mfma_f32_16x16x32_bf16(pa, vb, oacc[nt], 0, 0, 0);
    }
    __builtin_amdgcn_s_setprio(0);
  }
  __syncthreads();  // all waves done with K/V buffers before overlay

  // reduce lsum over quads (lane's lsum is for q=l15)
  lsum += __shfl_xor(lsum, 16, 64);
  lsum += __shfl_xor(lsum, 32, 64);

  float* OshF = (float*)smem;          // [8][16][68]
  float* lshF = OshF + 8 * 16 * 68;    // [8][16]
  if (lane < 16) lshF[w * 16 + lane] = lsum;
#pragma unroll
  for (int nt = 0; nt < 4; nt++)
#pragma unroll
    for (int r = 0; r < 4; r++)
      OshF[w * 1088 + (quad * 4 + r) * 68 + nt * 16 + l15] = oacc[nt][r];
  __syncthreads();

  // combine the two KV halves, normalize, write concat (bf16)
  const int q = tid >> 3;            // 0..63
  const int dv0 = (tid & 7) * 8;
  const int wa = q >> 4, wb = wa + 4, qr = q & 15;
  const float* pa = &OshF[wa * 1088 + qr * 68 + dv0];
  const float* pb = &OshF[wb * 1088 + qr * 68 + dv0];
  float4 a0 = *(const float4*)pa, a1 = *(const float4*)(pa + 4);
  float4 b0 = *(const float4*)pb, b1 = *(const float4*)(pb + 4);
  float li = 1.0f / (lshF[wa * 16 + qr] + lshF[wb * 16 + qr]);
  union { u16 hh[8]; uint4 u4; } o;
  o.hh[0] = f2bf((a0.x + b0.x) * li); o.hh[1] = f2bf((a0.y + b0.y) * li);
  o.hh[2] = f2bf((a0.z + b0.z) * li); o.hh[3] = f2bf((a0.w + b0.w) * li);
  o.hh[4] = f2bf((a1.x + b1.x) * li); o.hh[5] = f2bf((a1.y + b1.y) * li);
  o.hh[6] = f2bf((a1.z + b1.z) * li); o.hh[7] = f2bf((a1.w + b1.w) * li);
  *(uint4*)&conc[(size_t)(qblk + q) * D_MODEL + h * 64 + dv0] = o.u4;
}

// ---------- output GEMM: 64x64 tile, BK=64, 3-buf 2-deep counted-vmcnt ----------
// Per iter/wave: 4 gl16 -> s_waitcnt vmcnt(4) at top keeps it+1's loads in flight.
// sched_barrier(0)-after-s_barrier pins the schedule.
__global__ __launch_bounds__(256, 2) void out_gemm_k(
    const u16* __restrict__ A, const u16* __restrict__ Bt,
    const float* __restrict__ bias, float* __restrict__ out) {
  const int bid = blockIdx.x;
  const int l = (bid & 7) * 64 + (bid >> 3);   // bijective: 512 = 8*64
  const int m0 = (l >> 4) * 64, n0 = (l & 15) * 64;
  __shared__ __align__(16) u16 smem[6 * 4096];  // A x3 @0, B x3 @12288 (8KB each)
  const int tid = threadIdx.x;
  const int w = tid >> 6, lane = tid & 63, quad = lane >> 4, l15 = lane & 15;
  const int wm = (w >> 1) * 32, wn = (w & 1) * 32;
  const int pb = w * 128;

  f32x4 acc[2][2] = {};
  {  // prologue: k-step 0 -> buf0, k-step 1 -> buf1
#pragma unroll
    for (int e = 0; e < 2; e++) {
      int p = pb + e * 64 + lane;
      int r = p >> 3, cg = (p & 7) ^ (r & 7);
      gl16(&A[(size_t)(m0 + r) * D_MODEL + cg * 8], smem + (pb + e * 64) * 8);
      gl16(&Bt[(size_t)(n0 + r) * D_MODEL + cg * 8], smem + 12288 + (pb + e * 64) * 8);
    }
#pragma unroll
    for (int e = 0; e < 2; e++) {
      int p = pb + e * 64 + lane;
      int r = p >> 3, cg = (p & 7) ^ (r & 7);
      gl16(&A[(size_t)(m0 + r) * D_MODEL + 64 + cg * 8], smem + 4096 + (pb + e * 64) * 8);
      gl16(&Bt[(size_t)(n0 + r) * D_MODEL + 64 + cg * 8], smem + 16384 + (pb + e * 64) * 8);
    }
  }
#pragma unroll
  for (int it = 0; it < 16; it++) {
    const int rd = it % 3;  // compile-time constant after full unroll
    if (it < 15) asm volatile("s_waitcnt vmcnt(4)" ::: "memory");
    else         asm volatile("s_waitcnt vmcnt(0)" ::: "memory");
    __builtin_amdgcn_s_barrier();
    __builtin_amdgcn_sched_barrier(0);  // pin: nothing above barrier
    if (it < 14) {
      const int wr = (rd + 2) % 3;
      const int k0 = (it + 2) * 64;
      u16* As = smem + wr * 4096;
      u16* Bs = smem + 12288 + wr * 4096;
#pragma unroll
      for (int e = 0; e < 2; e++) {
        int p = pb + e * 64 + lane;
        int r = p >> 3, cg = (p & 7) ^ (r & 7);
        gl16(&A[(size_t)(m0 + r) * D_MODEL + k0 + cg * 8], As + (pb + e * 64) * 8);
        gl16(&Bt[(size_t)(n0 + r) * D_MODEL + k0 + cg * 8], Bs + (pb + e * 64) * 8);
      }
    }
    const u16* As = smem + rd * 4096;
    const u16* Bs = smem + 12288 + rd * 4096;
#pragma unroll
    for (int kc = 0; kc < 2; kc++) {
      const int c = kc * 4 + quad;
      bf16x8 af[2], bfr[2];
#pragma unroll
      for (int t = 0; t < 2; t++) {
        int ma = wm + t * 16 + l15, na = wn + t * 16 + l15;
        af[t] = *(const bf16x8*)&As[(ma * 8 + (c ^ (ma & 7))) * 8];
        bfr[t] = *(const bf16x8*)&Bs[(na * 8 + (c ^ (na & 7))) * 8];
      }
      __builtin_amdgcn_s_setprio(1);
#pragma unroll
      for (int tm = 0; tm < 2; tm++)
#pragma unroll
        for (int tn = 0; tn < 2; tn++)
          acc[tm][tn] = __builtin_amdgcn_mfma_f32_16x16x32_bf16(af[tm], bfr[tn], acc[tm][tn], 0, 0, 0);
      __builtin_amdgcn_s_setprio(0);
    }
  }
#pragma unroll
  for (int tm = 0; tm < 2; tm++)
#pragma unroll
    for (int tn = 0; tn < 2; tn++)
#pragma unroll
      for (int r = 0; r < 4; r++) {
        int row = m0 + wm + tm * 16 + quad * 4 + r;
        int col = n0 + wn + tn * 16 + l15;
        out[(size_t)row * D_MODEL + col] = acc[tm][tn][r] + bias[col];
      }
}

extern "C" void kernel_launch(void* const* d_in, const int* in_sizes, int n_in,
                              void* d_out, int out_size, void* d_ws, size_t ws_size,
                              hipStream_t stream) {
  const float* Q  = (const float*)d_in[0];
  const float* K  = (const float*)d_in[1];
  const float* V  = (const float*)d_in[2];
  const float* Wq = (const float*)d_in[3];
  const float* bq = (const float*)d_in[4];
  const float* Wk = (const float*)d_in[5];
  const float* bk = (const float*)d_in[6];
  const float* Wv = (const float*)d_in[7];
  const float* bv = (const float*)d_in[8];
  const float* Wo = (const float*)d_in[9];
  const float* bo = (const float*)d_in[10];
  float* out = (float*)d_out;

  u16* ws = (u16*)d_ws;
  u16* QKVb = ws;                                   // 3*S*D
  u16* Wqt  = QKVb + (size_t)3 * S_LEN * D_MODEL;   // D*D each
  u16* Wkt  = Wqt + (size_t)D_MODEL * D_MODEL;
  u16* Wvt  = Wkt + (size_t)D_MODEL * D_MODEL;
  u16* Wot  = Wvt + (size_t)D_MODEL * D_MODEL;
  u16* qbuf = Wot + (size_t)D_MODEL * D_MODEL;      // S*D
  u16* kbuf = qbuf + (size_t)S_LEN * D_MODEL;       // S*D
  u16* vTb  = kbuf + (size_t)S_LEN * D_MODEL;       // D*S
  u16* conc = vTb + (size_t)S_LEN * D_MODEL;        // S*D

  prep_k<<<dim3(10240), 256, 0, stream>>>(Q, K, V, Wq, Wk, Wv, Wo,
                                          QKVb, Wqt, Wkt, Wvt, Wot);
  proj_gemm_k<<<dim3(768), 256, 0, stream>>>(
      QKVb, Wqt, Wkt, Wvt, bq, bk, bv, qbuf, kbuf, vTb);
  attn_k<<<dim3(512), 512, 0, stream>>>(qbuf, kbuf, vTb, conc);
  out_gemm_k<<<dim3(512), 256, 0, stream>>>(conc, Wot, bo, out);
}

// Round 7
// 154.161 us; speedup vs baseline: 1.0770x; 1.0139x over previous
//
#include <hip/hip_runtime.h>
#include <stdint.h>

#define S_LEN 2048
#define D_MODEL 1024
#define NH 16
#define DKV 64

typedef unsigned short u16;
typedef __bf16 bf16x8 __attribute__((ext_vector_type(8)));
typedef float f32x4 __attribute__((ext_vector_type(4)));

__device__ __forceinline__ u16 f2bf(float f) {
  union { float f; uint32_t u; } v; v.f = f;
  uint32_t r = v.u + 0x7FFFu + ((v.u >> 16) & 1u);
  return (u16)(r >> 16);
}
// pack two positive floats to bf16x2 (cheap round; softmax-normalized later)
// NOTE round-3/4 post-mortem: hand-asm v_cvt_pk/v_exp here caused a deterministic
// trans-hazard corruption (compiler can't insert wait-states inside opaque asm).
// Use compiler-known ops only.
__device__ __forceinline__ uint32_t pkbf(float lo, float hi) {
  union { float f; uint32_t u; } a, b; a.f = lo; b.f = hi;
  return ((b.u + 0x8000u) & 0xFFFF0000u) | ((a.u + 0x8000u) >> 16);
}
// async global->LDS 16B: lds dest is WAVE-UNIFORM base; HW adds lane*16
__device__ __forceinline__ void gl16(const u16* g, u16* l) {
  __builtin_amdgcn_global_load_lds(
      (const __attribute__((address_space(1))) unsigned int*)g,
      (__attribute__((address_space(3))) unsigned int*)l, 16, 0, 0);
}

// ---------- fused preprocessing: conv QKV + transpose Wq/Wk/Wv + transpose Wo ----------
// 1D grid: [0,6144) conv, [6144,9216) qkvw transpose, [9216,10240) Wo transpose
__global__ __launch_bounds__(256) void prep_k(
    const float* __restrict__ Q, const float* __restrict__ K,
    const float* __restrict__ V, const float* __restrict__ Wq,
    const float* __restrict__ Wk, const float* __restrict__ Wv,
    const float* __restrict__ Wo, u16* __restrict__ QKVb,
    u16* __restrict__ Wqt, u16* __restrict__ Wkt, u16* __restrict__ Wvt,
    u16* __restrict__ Wot) {
  __shared__ float tile[32][33];
  const int idx = blockIdx.x;
  if (idx < 6144) {
    const int z = idx >> 11, blk = idx & 2047;
    const float* src = (z == 0) ? Q : (z == 1) ? K : V;
    u16* dst = QKVb + (size_t)z * S_LEN * D_MODEL;
    size_t i = ((size_t)blk * 256 + threadIdx.x) * 4;
    const float4 v = *(const float4*)(src + i);
    union { u16 h[4]; uint2 u2; } o;
    o.h[0] = f2bf(v.x); o.h[1] = f2bf(v.y); o.h[2] = f2bf(v.z); o.h[3] = f2bf(v.w);
    *(uint2*)(dst + i) = o.u2;
    return;
  }
  const float* ip; u16* op; int R, C, r0, c0;
  if (idx < 9216) {
    int t = idx - 6144;
    int which = t >> 10, head = (t & 1023) >> 6, tl = t & 63;
    ip = ((which == 0) ? Wq : (which == 1) ? Wk : Wv) + (size_t)head * D_MODEL * DKV;
    op = ((which == 0) ? Wqt : (which == 1) ? Wkt : Wvt) + (size_t)head * D_MODEL * DKV;
    R = D_MODEL; C = DKV; c0 = (tl & 1) * 32; r0 = (tl >> 1) * 32;
  } else {
    int t = idx - 9216;
    ip = Wo; op = Wot; R = D_MODEL; C = D_MODEL;
    c0 = (t & 31) * 32; r0 = (t >> 5) * 32;
  }
  int tr = threadIdx.x >> 5, tc = threadIdx.x & 31;
#pragma unroll
  for (int i = 0; i < 4; i++)
    tile[tr + i * 8][tc] = ip[(size_t)(r0 + tr + i * 8) * C + c0 + tc];
  __syncthreads();
#pragma unroll
  for (int i = 0; i < 4; i++) {
    int c = tr + i * 8;
    op[(size_t)(c0 + c) * R + r0 + tc] = f2bf(tile[tc][c]);
  }
}

// ---------- projection GEMM: 128x64 tile, BK=64, 3-buf 2-deep counted-vmcnt ----------
// Grid 768 = 3 blocks/CU exactly. XCD-swizzled: l = (bid%8)*96 + bid/8.
__global__ __launch_bounds__(256, 2) void proj_gemm_k(
    const u16* __restrict__ qkvb, const u16* __restrict__ Wqt,
    const u16* __restrict__ Wkt, const u16* __restrict__ Wvt,
    const float* __restrict__ bq, const float* __restrict__ bk,
    const float* __restrict__ bv,
    u16* __restrict__ qb, u16* __restrict__ kb, u16* __restrict__ vT) {
  const int bid = blockIdx.x;
  const int l = (bid & 7) * 96 + (bid >> 3);   // bijective: 768 = 8*96
  const int z = l >> 8, rem = l & 255;
  const int m0 = (rem >> 4) * 128, n0 = (rem & 15) * 64;
  const u16* A = qkvb + (size_t)z * S_LEN * D_MODEL;
  const u16* Bt = (z == 0) ? Wqt : (z == 1) ? Wkt : Wvt;
  const float* bias = (z == 0) ? bq : (z == 1) ? bk : bv;
  const float scale = (z == 0) ? 0.18033688f : 1.0f;  // (1/8)*log2(e) folded into q

  // u16: A x3 bufs @0 (16KB each), B x3 bufs @24576 (8KB each) -> 72KB, 2 blocks/CU
  __shared__ __align__(16) u16 smem[36864];
  const int tid = threadIdx.x;
  const int w = tid >> 6, lane = tid & 63, quad = lane >> 4, l15 = lane & 15;
  const int wm = (w >> 1) * 64, wn = (w & 1) * 32;
  const int pbA = w * 256, pbB = w * 128;

  f32x4 acc[4][2] = {};

  {  // prologue: k-step 0 -> buf0, k-step 1 -> buf1 (program order = vmcnt order)
#pragma unroll
    for (int b = 0; b < 2; b++) {
      const int k0 = b * 64;
      u16* As = smem + b * 8192;
      u16* Bs = smem + 24576 + b * 4096;
#pragma unroll
      for (int e = 0; e < 4; e++) {
        int p = pbA + e * 64 + lane;
        int r = p >> 3, cg = (p & 7) ^ (r & 7);
        gl16(&A[(size_t)(m0 + r) * D_MODEL + k0 + cg * 8], As + (pbA + e * 64) * 8);
      }
#pragma unroll
      for (int e = 0; e < 2; e++) {
        int p = pbB + e * 64 + lane;
        int r = p >> 3, cg = (p & 7) ^ (r & 7);
        gl16(&Bt[(size_t)(n0 + r) * D_MODEL + k0 + cg * 8], Bs + (pbB + e * 64) * 8);
      }
    }
  }
#pragma unroll
  for (int it = 0; it < 16; it++) {
    const int rd = it % 3;  // compile-time constant after full unroll
    if (it < 15) asm volatile("s_waitcnt vmcnt(6)" ::: "memory");
    else         asm volatile("s_waitcnt vmcnt(0)" ::: "memory");
    __builtin_amdgcn_s_barrier();
    __builtin_amdgcn_sched_barrier(0);  // pin: nothing (esp. ds_read/gl16) above barrier
    if (it < 14) {
      const int wr = (rd + 2) % 3;
      const int k0 = (it + 2) * 64;
      u16* As = smem + wr * 8192;
      u16* Bs = smem + 24576 + wr * 4096;
#pragma unroll
      for (int e = 0; e < 4; e++) {
        int p = pbA + e * 64 + lane;
        int r = p >> 3, cg = (p & 7) ^ (r & 7);
        gl16(&A[(size_t)(m0 + r) * D_MODEL + k0 + cg * 8], As + (pbA + e * 64) * 8);
      }
#pragma unroll
      for (int e = 0; e < 2; e++) {
        int p = pbB + e * 64 + lane;
        int r = p >> 3, cg = (p & 7) ^ (r & 7);
        gl16(&Bt[(size_t)(n0 + r) * D_MODEL + k0 + cg * 8], Bs + (pbB + e * 64) * 8);
      }
    }
    const u16* As = smem + rd * 8192;
    const u16* Bs = smem + 24576 + rd * 4096;
#pragma unroll
    for (int kc = 0; kc < 2; kc++) {
      bf16x8 af[4], bfr[2];
      const int c = kc * 4 + quad;
#pragma unroll
      for (int t = 0; t < 4; t++) {
        int ma = wm + t * 16 + l15;
        af[t] = *(const bf16x8*)&As[(ma * 8 + (c ^ (ma & 7))) * 8];
      }
#pragma unroll
      for (int t = 0; t < 2; t++) {
        int na = wn + t * 16 + l15;
        bfr[t] = *(const bf16x8*)&Bs[(na * 8 + (c ^ (na & 7))) * 8];
      }
      __builtin_amdgcn_s_setprio(1);
#pragma unroll
      for (int tm = 0; tm < 4; tm++)
#pragma unroll
        for (int tn = 0; tn < 2; tn++)
          acc[tm][tn] = __builtin_amdgcn_mfma_f32_16x16x32_bf16(af[tm], bfr[tn], acc[tm][tn], 0, 0, 0);
      __builtin_amdgcn_s_setprio(0);
    }
  }

  if (z < 2) {
    u16* O = (z == 0) ? qb : kb;
#pragma unroll
    for (int tm = 0; tm < 4; tm++)
#pragma unroll
      for (int tn = 0; tn < 2; tn++)
#pragma unroll
        for (int r = 0; r < 4; r++) {
          int row = m0 + wm + tm * 16 + quad * 4 + r;
          int col = n0 + wn + tn * 16 + l15;
          O[(size_t)row * D_MODEL + col] = f2bf((acc[tm][tn][r] + bias[col]) * scale);
        }
  } else {
#pragma unroll
    for (int tm = 0; tm < 4; tm++)
#pragma unroll
      for (int tn = 0; tn < 2; tn++) {
        int col = n0 + wn + tn * 16 + l15;
        int row0 = m0 + wm + tm * 16 + quad * 4;
        float b = bias[col];
        union { u16 h[4]; uint2 u2; } o;
#pragma unroll
        for (int r = 0; r < 4; r++) o.h[r] = f2bf(acc[tm][tn][r] + b);
        *(uint2*)&vT[(size_t)col * S_LEN + row0] = o.u2;
      }
  }
}

// ---------- attention: 4-buf 3-DEEP counted-vmcnt, fully unrolled ----------
// Depth-2 (3-buf) exposed L3 latency: wait at top of it covered loads issued only
// 1 iter (~400cy) earlier vs 600-900cy L3-served K/V [m126]. 4-buf waits on loads
// issued 3 iters (~1200cy) earlier -> latency fully covered.
// P strip stride 56 u16 (112B: 16B-aligned b128, 28-bank stride -> 2-way only);
// LDS: K 32KB + V 32KB + P 14.3KB = 78.3KB -> 2 blocks/CU.
__global__ __launch_bounds__(512) void attn_k(
    const u16* __restrict__ qb, const u16* __restrict__ kb,
    const u16* __restrict__ vT, u16* __restrict__ conc) {
  const int bid = blockIdx.x;
  const int l = (bid & 7) * 64 + (bid >> 3);   // bijective: 512 = 8*64
  const int h = l >> 5, qblk = (l & 31) * 64;
  const int tid = threadIdx.x;
  const int w = tid >> 6, lane = tid & 63, quad = lane >> 4, l15 = lane & 15;
  const int half = w >> 2, wq = w & 3;
  const int q0 = qblk + wq * 16;

  // u16 layout: K[2 half][4 buf][2048] @0 (32KB), V[2][4][2048] @16384 (32KB),
  //             P[8][16*56] @32768 (14.3KB) -> 78KB total, 2 blocks/CU.
  // epilogue overlays @0 as float Osh[8][16][68] + lsh[8][16] (35.3KB)
  __shared__ __align__(16) u16 smem[39936];
  u16* Kh = smem + half * 8192;
  u16* Vh = smem + 16384 + half * 8192;
  u16* Pw = smem + 32768 + w * 896;

  // Q B-frags (n=q=l15, k=dk=kc*32+quad*8+j); q pre-scaled by (1/8)*log2(e)
  bf16x8 qf[2];
#pragma unroll
  for (int kc = 0; kc < 2; kc++)
    qf[kc] = *(const bf16x8*)&qb[(size_t)(q0 + l15) * D_MODEL + h * 64 + kc * 32 + quad * 8];

  const u16* kbase = kb + (size_t)h * 64;
  const u16* vbase = vT + (size_t)(h * 64) * S_LEN;

  // per-wave staging: 1 K chunk + 1 V chunk per lane per iter
  const int p = wq * 64 + lane;                   // 0..255
  const int kr = p >> 3, kcg = (p & 7) ^ (kr & 7);
  const int vr = p >> 2, vcg = (p & 3) ^ (vr & 3);
  const size_t kgoff = (size_t)kr * D_MODEL + kcg * 8;
  const size_t vgoff = (size_t)vr * S_LEN + vcg * 8;
  const int ldsoff = wq * 64 * 8;                 // wave-uniform dest (HW adds lane*16)

  f32x4 oacc[4] = {};
  float lsum = 0.f;

  {  // prologue: stage slots 0,1,2 (program order = vmcnt order)
#pragma unroll
    for (int s = 0; s < 3; s++) {
      const int t0 = half * 1024 + s * 32;
      gl16(kbase + (size_t)t0 * D_MODEL + kgoff, Kh + s * 2048 + ldsoff);
      gl16(vbase + t0 + vgoff, Vh + s * 2048 + ldsoff);
    }
  }

#pragma unroll
  for (int it = 0; it < 32; it++) {
    const int rd = it & 3;  // compile-time constant after full unroll
    // retire buf[rd]'s loads (issued 3 iters ago); keep up to 4 (slots it+1,it+2) in flight
    if (it < 30)       asm volatile("s_waitcnt vmcnt(4)" ::: "memory");
    else if (it == 30) asm volatile("s_waitcnt vmcnt(2)" ::: "memory");
    else               asm volatile("s_waitcnt vmcnt(0)" ::: "memory");
    __builtin_amdgcn_s_barrier();   // now ALL waves' buf[rd] chunks visible
    __builtin_amdgcn_sched_barrier(0);  // pin: nothing (esp. ds_read/gl16) above barrier
    if (it < 29) {                  // prefetch it+3 into buf[(it+3)&3] = buf[(it-1)&3]
      const int wr = (it + 3) & 3;
      const int t0n = half * 1024 + (it + 3) * 32;
      gl16(kbase + (size_t)t0n * D_MODEL + kgoff, Kh + wr * 2048 + ldsoff);
      gl16(vbase + t0n + vgoff, Vh + wr * 2048 + ldsoff);
    }
    const u16* Kc = Kh + rd * 2048;
    const u16* Vc = Vh + rd * 2048;

    // Sᵀ = K·Qᵀ : 2 independent chains (tn), depth 2 (kc)
    f32x4 sacc[2] = {};
    __builtin_amdgcn_s_setprio(1);
#pragma unroll
    for (int kc = 0; kc < 2; kc++)
#pragma unroll
      for (int tn = 0; tn < 2; tn++) {
        int rr = tn * 16 + l15;
        bf16x8 ka = *(const bf16x8*)&Kc[(rr * 8 + ((kc * 4 + quad) ^ (rr & 7))) * 8];
        sacc[tn] = __builtin_amdgcn_mfma_f32_16x16x32_bf16(ka, qf[kc], sacc[tn], 0, 0, 0);
      }
    __builtin_amdgcn_s_setprio(0);

    // p = 2^s (log2e folded into q); lane holds Sᵀ[t=tn*16+quad*4+r][q=l15]
#pragma unroll
    for (int tn = 0; tn < 2; tn++) {
      float p0 = __builtin_amdgcn_exp2f(sacc[tn][0]);
      float p1 = __builtin_amdgcn_exp2f(sacc[tn][1]);
      float p2 = __builtin_amdgcn_exp2f(sacc[tn][2]);
      float p3 = __builtin_amdgcn_exp2f(sacc[tn][3]);
      lsum += (p0 + p1) + (p2 + p3);
      uint2 pw2; pw2.x = pkbf(p0, p1); pw2.y = pkbf(p2, p3);
      *(uint2*)&Pw[l15 * 56 + tn * 16 + quad * 4] = pw2;
    }

    // O += P·V : 4 fully independent chains (nt), k=32 (one MFMA each)
    bf16x8 pa = *(const bf16x8*)&Pw[l15 * 56 + quad * 8];
    __builtin_amdgcn_s_setprio(1);
#pragma unroll
    for (int nt = 0; nt < 4; nt++) {
      int dv = nt * 16 + l15;
      bf16x8 vb = *(const bf16x8*)&Vc[(dv * 4 + (quad ^ (dv & 3))) * 8];
      oacc[nt] = __builtin_amdgcn_mfma_f32_16x16x32_bf16(pa, vb, oacc[nt], 0, 0, 0);
    }
    __builtin_amdgcn_s_setprio(0);
  }
  __syncthreads();  // all waves done with K/V buffers before overlay

  // reduce lsum over quads (lane's lsum is for q=l15)
  lsum += __shfl_xor(lsum, 16, 64);
  lsum += __shfl_xor(lsum, 32, 64);

  float* OshF = (float*)smem;          // [8][16][68]
  float* lshF = OshF + 8 * 16 * 68;    // [8][16]
  if (lane < 16) lshF[w * 16 + lane] = lsum;
#pragma unroll
  for (int nt = 0; nt < 4; nt++)
#pragma unroll
    for (int r = 0; r < 4; r++)
      OshF[w * 1088 + (quad * 4 + r) * 68 + nt * 16 + l15] = oacc[nt][r];
  __syncthreads();

  // combine the two KV halves, normalize, write concat (bf16)
  const int q = tid >> 3;            // 0..63
  const int dv0 = (tid & 7) * 8;
  const int wa = q >> 4, wb = wa + 4, qr = q & 15;
  const float* pa = &OshF[wa * 1088 + qr * 68 + dv0];
  const float* pb = &OshF[wb * 1088 + qr * 68 + dv0];
  float4 a0 = *(const float4*)pa, a1 = *(const float4*)(pa + 4);
  float4 b0 = *(const float4*)pb, b1 = *(const float4*)(pb + 4);
  float li = 1.0f / (lshF[wa * 16 + qr] + lshF[wb * 16 + qr]);
  union { u16 hh[8]; uint4 u4; } o;
  o.hh[0] = f2bf((a0.x + b0.x) * li); o.hh[1] = f2bf((a0.y + b0.y) * li);
  o.hh[2] = f2bf((a0.z + b0.z) * li); o.hh[3] = f2bf((a0.w + b0.w) * li);
  o.hh[4] = f2bf((a1.x + b1.x) * li); o.hh[5] = f2bf((a1.y + b1.y) * li);
  o.hh[6] = f2bf((a1.z + b1.z) * li); o.hh[7] = f2bf((a1.w + b1.w) * li);
  *(uint4*)&conc[(size_t)(qblk + q) * D_MODEL + h * 64 + dv0] = o.u4;
}

// ---------- output GEMM: 64x64 tile, BK=64, 4-buf 3-DEEP counted-vmcnt ----------
// Per iter/wave: 4 gl16; top-of-iter vmcnt(8) keeps slots it+1,it+2 in flight
// (3-iter slack covers L3 latency). A[4] @0, B[4] @16384; 64KB LDS.
__global__ __launch_bounds__(256, 2) void out_gemm_k(
    const u16* __restrict__ A, const u16* __restrict__ Bt,
    const float* __restrict__ bias, float* __restrict__ out) {
  const int bid = blockIdx.x;
  const int l = (bid & 7) * 64 + (bid >> 3);   // bijective: 512 = 8*64
  const int m0 = (l >> 4) * 64, n0 = (l & 15) * 64;
  __shared__ __align__(16) u16 smem[8 * 4096];  // A x4 @0, B x4 @16384 (8KB each)
  const int tid = threadIdx.x;
  const int w = tid >> 6, lane = tid & 63, quad = lane >> 4, l15 = lane & 15;
  const int wm = (w >> 1) * 32, wn = (w & 1) * 32;
  const int pb = w * 128;

  f32x4 acc[2][2] = {};
  {  // prologue: stage k-slots 0,1,2 (program order = vmcnt order)
#pragma unroll
    for (int s = 0; s < 3; s++) {
      const int k0 = s * 64;
#pragma unroll
      for (int e = 0; e < 2; e++) {
        int p = pb + e * 64 + lane;
        int r = p >> 3, cg = (p & 7) ^ (r & 7);
        gl16(&A[(size_t)(m0 + r) * D_MODEL + k0 + cg * 8], smem + s * 4096 + (pb + e * 64) * 8);
        gl16(&Bt[(size_t)(n0 + r) * D_MODEL + k0 + cg * 8], smem + 16384 + s * 4096 + (pb + e * 64) * 8);
      }
    }
  }
#pragma unroll
  for (int it = 0; it < 16; it++) {
    const int rd = it & 3;  // compile-time constant after full unroll
    if (it < 14)       asm volatile("s_waitcnt vmcnt(8)" ::: "memory");
    else if (it == 14) asm volatile("s_waitcnt vmcnt(4)" ::: "memory");
    else               asm volatile("s_waitcnt vmcnt(0)" ::: "memory");
    __builtin_amdgcn_s_barrier();
    __builtin_amdgcn_sched_barrier(0);  // pin: nothing above barrier
    if (it < 13) {
      const int wr = (it + 3) & 3;
      const int k0 = (it + 3) * 64;
      u16* As = smem + wr * 4096;
      u16* Bs = smem + 16384 + wr * 4096;
#pragma unroll
      for (int e = 0; e < 2; e++) {
        int p = pb + e * 64 + lane;
        int r = p >> 3, cg = (p & 7) ^ (r & 7);
        gl16(&A[(size_t)(m0 + r) * D_MODEL + k0 + cg * 8], As + (pb + e * 64) * 8);
        gl16(&Bt[(size_t)(n0 + r) * D_MODEL + k0 + cg * 8], Bs + (pb + e * 64) * 8);
      }
    }
    const u16* As = smem + rd * 4096;
    const u16* Bs = smem + 16384 + rd * 4096;
#pragma unroll
    for (int kc = 0; kc < 2; kc++) {
      const int c = kc * 4 + quad;
      bf16x8 af[2], bfr[2];
#pragma unroll
      for (int t = 0; t < 2; t++) {
        int ma = wm + t * 16 + l15, na = wn + t * 16 + l15;
        af[t] = *(const bf16x8*)&As[(ma * 8 + (c ^ (ma & 7))) * 8];
        bfr[t] = *(const bf16x8*)&Bs[(na * 8 + (c ^ (na & 7))) * 8];
      }
      __builtin_amdgcn_s_setprio(1);
#pragma unroll
      for (int tm = 0; tm < 2; tm++)
#pragma unroll
        for (int tn = 0; tn < 2; tn++)
          acc[tm][tn] = __builtin_amdgcn_mfma_f32_16x16x32_bf16(af[tm], bfr[tn], acc[tm][tn], 0, 0, 0);
      __builtin_amdgcn_s_setprio(0);
    }
  }
#pragma unroll
  for (int tm = 0; tm < 2; tm++)
#pragma unroll
    for (int tn = 0; tn < 2; tn++)
#pragma unroll
      for (int r = 0; r < 4; r++) {
        int row = m0 + wm + tm * 16 + quad * 4 + r;
        int col = n0 + wn + tn * 16 + l15;
        out[(size_t)row * D_MODEL + col] = acc[tm][tn][r] + bias[col];
      }
}

extern "C" void kernel_launch(void* const* d_in, const int* in_sizes, int n_in,
                              void* d_out, int out_size, void* d_ws, size_t ws_size,
                              hipStream_t stream) {
  const float* Q  = (const float*)d_in[0];
  const float* K  = (const float*)d_in[1];
  const float* V  = (const float*)d_in[2];
  const float* Wq = (const float*)d_in[3];
  const float* bq = (const float*)d_in[4];
  const float* Wk = (const float*)d_in[5];
  const float* bk = (const float*)d_in[6];
  const float* Wv = (const float*)d_in[7];
  const float* bv = (const float*)d_in[8];
  const float* Wo = (const float*)d_in[9];
  const float* bo = (const float*)d_in[10];
  float* out = (float*)d_out;

  u16* ws = (u16*)d_ws;
  u16* QKVb = ws;                                   // 3*S*D
  u16* Wqt  = QKVb + (size_t)3 * S_LEN * D_MODEL;   // D*D each
  u16* Wkt  = Wqt + (size_t)D_MODEL * D_MODEL;
  u16* Wvt  = Wkt + (size_t)D_MODEL * D_MODEL;
  u16* Wot  = Wvt + (size_t)D_MODEL * D_MODEL;
  u16* qbuf = Wot + (size_t)D_MODEL * D_MODEL;      // S*D
  u16* kbuf = qbuf + (size_t)S_LEN * D_MODEL;       // S*D
  u16* vTb  = kbuf + (size_t)S_LEN * D_MODEL;       // D*S
  u16* conc = vTb + (size_t)S_LEN * D_MODEL;        // S*D

  prep_k<<<dim3(10240), 256, 0, stream>>>(Q, K, V, Wq, Wk, Wv, Wo,
                                          QKVb, Wqt, Wkt, Wvt, Wot);
  proj_gemm_k<<<dim3(768), 256, 0, stream>>>(
      QKVb, Wqt, Wkt, Wvt, bq, bk, bv, qbuf, kbuf, vTb);
  attn_k<<<dim3(512), 512, 0, stream>>>(qbuf, kbuf, vTb, conc);
  out_gemm_k<<<dim3(512), 256, 0, stream>>>(conc, Wot, bo, out);
}